// Round 1
// baseline (388.999 us; speedup 1.0000x reference)
//
#include <hip/hip_runtime.h>
#include <stdint.h>

#define S_LEN 2048
#define BATCH 2
#define HID 2048
#define NH 16
#define NKV 8
#define HD 128
#define WINDOW 1024
#define SCALE 0.08838834764831845f

typedef unsigned short u16;
typedef unsigned int u32;
typedef __attribute__((ext_vector_type(8))) short short8;
typedef __attribute__((ext_vector_type(4))) float f32x4;
typedef __attribute__((ext_vector_type(4))) u16 u16x4;

__device__ __forceinline__ u16 f2b(float f) {
  u32 u = __builtin_bit_cast(u32, f);
  return (u16)((u + 0x7fffu + ((u >> 16) & 1u)) >> 16);
}
__device__ __forceinline__ float b2f(u16 h) {
  u32 u = ((u32)h) << 16;
  return __builtin_bit_cast(float, u);
}

__device__ __forceinline__ void gload_lds16(const u16* g, u16* l) {
  __builtin_amdgcn_global_load_lds(
      (const __attribute__((address_space(1))) u32*)g,
      (__attribute__((address_space(3))) u32*)l, 16, 0, 0);
}

// ---------------- f32 -> bf16 convert ----------------
__global__ __launch_bounds__(256) void k_conv(const float* __restrict__ src,
                                              u16* __restrict__ dst, int n4) {
  int i = blockIdx.x * blockDim.x + threadIdx.x;
  int st = gridDim.x * blockDim.x;
  for (; i < n4; i += st) {
    f32x4 v = ((const f32x4*)src)[i];
    u16x4 o;
    o[0] = f2b(v[0]); o[1] = f2b(v[1]); o[2] = f2b(v[2]); o[3] = f2b(v[3]);
    ((u16x4*)dst)[i] = o;
  }
}

// ---------------- GEMM C = A * B^T ----------------
// A: M x K bf16 row-major; B: N x K bf16 row-major; C: M x N (bf16 or f32)
// 128x128 tile, BK=32, 256 threads (4 waves as 2x2 of 64x64).
__device__ __forceinline__ void store_c(u16* C, long idx, float v) { C[idx] = f2b(v); }
__device__ __forceinline__ void store_c(float* C, long idx, float v) { C[idx] = v; }

template <typename OutT>
__global__ __launch_bounds__(256) void k_gemm_bt(const u16* __restrict__ A,
                                                 const u16* __restrict__ B,
                                                 OutT* __restrict__ C,
                                                 int M, int N, int K) {
  __shared__ u16 sA[128 * 32];
  __shared__ u16 sB[128 * 32];
  const int tid = threadIdx.x;
  const int lane = tid & 63;
  const int l15 = lane & 15;
  const int lg = lane >> 4;
  const int w = tid >> 6;
  const int wr = w >> 1;
  const int wc = w & 1;
  const long m0 = (long)blockIdx.y * 128;
  const long n0 = (long)blockIdx.x * 128;

  f32x4 acc[4][4];
  const f32x4 z4 = {0.f, 0.f, 0.f, 0.f};
#pragma unroll
  for (int i = 0; i < 4; ++i)
#pragma unroll
    for (int j = 0; j < 4; ++j) acc[i][j] = z4;

  const int c0 = tid, c1 = tid + 256;           // 512 chunks of 16B per tile
  const u16* gA0 = A + (m0 + (c0 >> 2)) * K + (c0 & 3) * 8;
  const u16* gA1 = A + (m0 + (c1 >> 2)) * K + (c1 & 3) * 8;
  const u16* gB0 = B + (n0 + (c0 >> 2)) * K + (c0 & 3) * 8;
  const u16* gB1 = B + (n0 + (c1 >> 2)) * K + (c1 & 3) * 8;
  u16* lA0 = &sA[c0 * 8]; u16* lA1 = &sA[c1 * 8];
  u16* lB0 = &sB[c0 * 8]; u16* lB1 = &sB[c1 * 8];

  for (int k0 = 0; k0 < K; k0 += 32) {
    gload_lds16(gA0 + k0, lA0);
    gload_lds16(gA1 + k0, lA1);
    gload_lds16(gB0 + k0, lB0);
    gload_lds16(gB1 + k0, lB1);
    __syncthreads();
    short8 aF[4], bF[4];
#pragma unroll
    for (int i = 0; i < 4; ++i)
      aF[i] = *(const short8*)&sA[(wr * 64 + i * 16 + l15) * 32 + lg * 8];
#pragma unroll
    for (int j = 0; j < 4; ++j)
      bF[j] = *(const short8*)&sB[(wc * 64 + j * 16 + l15) * 32 + lg * 8];
#pragma unroll
    for (int i = 0; i < 4; ++i)
#pragma unroll
      for (int j = 0; j < 4; ++j)
        acc[i][j] = __builtin_amdgcn_mfma_f32_16x16x32_bf16(aF[i], bF[j], acc[i][j], 0, 0, 0);
    __syncthreads();
  }

#pragma unroll
  for (int i = 0; i < 4; ++i)
#pragma unroll
    for (int j = 0; j < 4; ++j)
#pragma unroll
      for (int r = 0; r < 4; ++r) {
        long row = m0 + wr * 64 + i * 16 + lg * 4 + r;
        long col = n0 + wc * 64 + j * 16 + l15;
        store_c(C, row * N + col, acc[i][j][r]);
      }
}

// ---------------- RMSNorm + RoPE (in place, bf16) ----------------
// rows [0, B*S*NH): Q rows; rows [B*S*NH, B*S*(NH+NKV)): K rows.
__global__ __launch_bounds__(256) void k_normrope(u16* __restrict__ Qb,
                                                  u16* __restrict__ Kb,
                                                  const float* __restrict__ cosb,
                                                  const float* __restrict__ sinb,
                                                  const float* __restrict__ qw,
                                                  const float* __restrict__ kw) {
  const int lane = threadIdx.x & 63;
  const int w = threadIdx.x >> 6;
  int row = blockIdx.x * 4 + w;
  const int nQ = BATCH * S_LEN * NH;
  u16* p;
  const float* nw;
  int tok;
  if (row < nQ) {
    tok = row / NH;
    int h = row - tok * NH;
    p = Qb + (long)tok * (NH * HD) + h * HD;
    nw = qw;
  } else {
    int r2 = row - nQ;
    tok = r2 / NKV;
    int h = r2 - tok * NKV;
    p = Kb + (long)tok * (NKV * HD) + h * HD;
    nw = kw;
  }
  float x0 = b2f(p[lane]);
  float x1 = b2f(p[lane + 64]);
  float ss = x0 * x0 + x1 * x1;
#pragma unroll
  for (int mk = 1; mk < 64; mk <<= 1) ss += __shfl_xor(ss, mk, 64);
  float rinv = rsqrtf(ss * (1.0f / 128.0f) + 1e-6f);
  float y0 = x0 * rinv * nw[lane];
  float y1 = x1 * rinv * nw[lane + 64];
  const float* cp = cosb + (long)tok * HD;
  const float* sp = sinb + (long)tok * HD;
  float o0 = y0 * cp[lane] - y1 * sp[lane];
  float o1 = y1 * cp[lane + 64] + y0 * sp[lane + 64];
  p[lane] = f2b(o0);
  p[lane + 64] = f2b(o1);
}

// ---------------- Flash attention ----------------
// grid (S/64, NH, B); 256 threads = 4 waves; wave w owns q-rows [q0+16w, q0+16w+16).
// KV tiles of 32. K staged via global_load_lds with XOR-swizzled source chunks;
// V staged transposed via registers into XOR-subtiled layout.
__global__ __launch_bounds__(256) void k_attn(const u16* __restrict__ Q,
                                              const u16* __restrict__ Kb,
                                              const u16* __restrict__ Vb,
                                              u16* __restrict__ AO) {
  __shared__ u16 sK[32 * 128];     // [r][128] with dchunk^(r&7) swizzle, 8KB
  __shared__ u16 sV[32 * 128];     // subtiled: elem(r,d) at (d*4 + ((r>>3)^((d>>3)&3)))*8 + (r&7)
  __shared__ u16 sP[4][16 * 40];   // per-wave P tile, row stride 40
  const int tid = threadIdx.x;
  const int lane = tid & 63;
  const int l15 = lane & 15;
  const int lg = lane >> 4;
  const int w = tid >> 6;
  const int q0 = blockIdx.x * 64;
  const int h = blockIdx.y;
  const int b = blockIdx.z;
  const int kvh = h >> 1;

  // Q fragments (A-operand): row l15 of wave's 16 rows, d = c*32 + lg*8 + j
  const u16* qp = Q + (long)(b * S_LEN + q0 + w * 16 + l15) * (NH * HD) + h * HD;
  short8 qF[4];
#pragma unroll
  for (int c = 0; c < 4; ++c) qF[c] = *(const short8*)(qp + c * 32 + lg * 8);

  float m[4], lsum[4];
  f32x4 o[8];
  const f32x4 z4 = {0.f, 0.f, 0.f, 0.f};
#pragma unroll
  for (int r = 0; r < 4; ++r) { m[r] = 0.f; lsum[r] = 0.f; }
#pragma unroll
  for (int n = 0; n < 8; ++n) o[n] = z4;

  int lo = q0 - (WINDOW - 1);
  if (lo < 0) lo = 0;
  const int t_lo = lo >> 5;
  const int t_hi = (q0 + 63) >> 5;

  // K staging chunks: 512 chunks of 16B; chunk c: row = c>>4, lds dchunk = c&15,
  // global dchunk = (c&15) ^ (row&7)  (involution; read applies same XOR).
  const int cc0 = tid, cc1 = tid + 256;
  const int kr0 = cc0 >> 4, kd0 = (cc0 & 15) ^ (kr0 & 7);
  const int kr1 = cc1 >> 4, kd1 = (cc1 & 15) ^ (kr1 & 7);
  const u16* kbase = Kb + (long)(b * S_LEN) * (NKV * HD) + kvh * HD;
  // V staging: thread -> rows (vr0, vr0+1), cols d0..d0+7
  const int vr0 = (tid >> 4) * 2;
  const int vd0 = (tid & 15) * 8;   // (d>>3) = tid&15 for all 8 d's
  const u16* vbase = Vb + (long)(b * S_LEN) * (NKV * HD) + kvh * HD;

  for (int t = t_lo; t <= t_hi; ++t) {
    const int kv0 = t << 5;
    gload_lds16(kbase + (long)(kv0 + kr0) * (NKV * HD) + kd0 * 8, &sK[cc0 * 8]);
    gload_lds16(kbase + (long)(kv0 + kr1) * (NKV * HD) + kd1 * 8, &sK[cc1 * 8]);
    {
      const u16* vp = vbase + (long)(kv0 + vr0) * (NKV * HD) + vd0;
      short8 v0 = *(const short8*)vp;
      short8 v1 = *(const short8*)(vp + NKV * HD);
      const int mlo = (tid & 15) & 3;  // (d>>3)&3
#pragma unroll
      for (int e = 0; e < 8; ++e) {
        int d = vd0 + e;
        u32 pk = (u32)(u16)v0[e] | ((u32)(u16)v1[e] << 16);
        int unit = d * 4 + ((vr0 >> 3) ^ mlo);
        *(u32*)&sV[unit * 8 + (vr0 & 7)] = pk;
      }
    }
    __syncthreads();

    // ---- QK^T ----
    f32x4 sc[2];
    sc[0] = z4; sc[1] = z4;
#pragma unroll
    for (int nt = 0; nt < 2; ++nt) {
      const int krow = nt * 16 + l15;
#pragma unroll
      for (int c = 0; c < 4; ++c) {
        const int dch = (c * 4 + lg) ^ (krow & 7);
        short8 kf = *(const short8*)&sK[krow * 128 + dch * 8];
        sc[nt] = __builtin_amdgcn_mfma_f32_16x16x32_bf16(qF[c], kf, sc[nt], 0, 0, 0);
      }
    }

    // ---- mask + scale + online softmax ----
    float pv[2][4], tm[4];
#pragma unroll
    for (int r = 0; r < 4; ++r) {
      const int i = q0 + w * 16 + lg * 4 + r;
#pragma unroll
      for (int nt = 0; nt < 2; ++nt) {
        const int j = kv0 + nt * 16 + l15;
        const bool ok = (j <= i) && (i - j < WINDOW);
        pv[nt][r] = ok ? sc[nt][r] * SCALE : -1e30f;
      }
      tm[r] = fmaxf(pv[0][r], pv[1][r]);
    }
#pragma unroll
    for (int r = 0; r < 4; ++r) {
#pragma unroll
      for (int mk = 1; mk < 16; mk <<= 1) tm[r] = fmaxf(tm[r], __shfl_xor(tm[r], mk, 64));
    }
    float alpha[4], rs[4];
#pragma unroll
    for (int r = 0; r < 4; ++r) {
      const float mn = fmaxf(m[r], tm[r]);
      alpha[r] = __expf(m[r] - mn);
      m[r] = mn;
      const float p0 = __expf(pv[0][r] - mn);
      const float p1 = __expf(pv[1][r] - mn);
      rs[r] = p0 + p1;
      sP[w][(lg * 4 + r) * 40 + l15] = f2b(p0);
      sP[w][(lg * 4 + r) * 40 + 16 + l15] = f2b(p1);
    }
#pragma unroll
    for (int r = 0; r < 4; ++r) {
#pragma unroll
      for (int mk = 1; mk < 16; mk <<= 1) rs[r] += __shfl_xor(rs[r], mk, 64);
      lsum[r] = lsum[r] * alpha[r] + rs[r];
    }
#pragma unroll
    for (int n = 0; n < 8; ++n) {
      f32x4 t4 = o[n];
      t4[0] *= alpha[0]; t4[1] *= alpha[1]; t4[2] *= alpha[2]; t4[3] *= alpha[3];
      o[n] = t4;
    }

    // ---- PV ----
    const short8 pF = *(const short8*)&sP[w][l15 * 40 + lg * 8];
#pragma unroll
    for (int n = 0; n < 8; ++n) {
      const int d = n * 16 + l15;
      const int unit = d * 4 + (lg ^ ((d >> 3) & 3));
      const short8 vF = *(const short8*)&sV[unit * 8];
      o[n] = __builtin_amdgcn_mfma_f32_16x16x32_bf16(pF, vF, o[n], 0, 0, 0);
    }
    __syncthreads();
  }

  // epilogue
#pragma unroll
  for (int n = 0; n < 8; ++n)
#pragma unroll
    for (int r = 0; r < 4; ++r) {
      long row = (long)(b * S_LEN + q0 + w * 16 + lg * 4 + r);
      AO[row * (NH * HD) + h * HD + n * 16 + l15] = f2b(o[n][r] / lsum[r]);
    }
}

// ---------------- launch ----------------
extern "C" void kernel_launch(void* const* d_in, const int* in_sizes, int n_in,
                              void* d_out, int out_size, void* d_ws, size_t ws_size,
                              hipStream_t stream) {
  const float* hs   = (const float*)d_in[0];
  const float* cosb = (const float*)d_in[1];
  const float* sinb = (const float*)d_in[2];
  const float* Wq   = (const float*)d_in[3];
  const float* Wk   = (const float*)d_in[4];
  const float* Wv   = (const float*)d_in[5];
  const float* Wo   = (const float*)d_in[6];
  const float* qw   = (const float*)d_in[7];
  const float* kw   = (const float*)d_in[8];
  float* out = (float*)d_out;

  const long SZ_X  = (long)BATCH * S_LEN * HID;        // 8M
  const long SZ_WQ = (long)NH * HD * HID;              // 4M
  const long SZ_WK = (long)NKV * HD * HID;             // 2M
  u16* Xb  = (u16*)d_ws;
  u16* Wqb = Xb + SZ_X;
  u16* Wkb = Wqb + SZ_WQ;
  u16* Wvb = Wkb + SZ_WK;
  u16* Wob = Wvb + SZ_WK;
  u16* Qb  = Wob + SZ_WQ;
  u16* Kb  = Qb + SZ_X;
  u16* Vb  = Kb + (long)BATCH * S_LEN * NKV * HD;
  u16* AOb = Vb + (long)BATCH * S_LEN * NKV * HD;

  k_conv<<<2048, 256, 0, stream>>>(hs, Xb, (int)(SZ_X / 4));
  k_conv<<<1024, 256, 0, stream>>>(Wq, Wqb, (int)(SZ_WQ / 4));
  k_conv<<<512, 256, 0, stream>>>(Wk, Wkb, (int)(SZ_WK / 4));
  k_conv<<<512, 256, 0, stream>>>(Wv, Wvb, (int)(SZ_WK / 4));
  k_conv<<<1024, 256, 0, stream>>>(Wo, Wob, (int)(SZ_WQ / 4));

  dim3 blk(256);
  k_gemm_bt<u16><<<dim3(16, 32), blk, 0, stream>>>(Xb, Wqb, Qb, BATCH * S_LEN, NH * HD, HID);
  k_gemm_bt<u16><<<dim3(8, 32), blk, 0, stream>>>(Xb, Wkb, Kb, BATCH * S_LEN, NKV * HD, HID);
  k_gemm_bt<u16><<<dim3(8, 32), blk, 0, stream>>>(Xb, Wvb, Vb, BATCH * S_LEN, NKV * HD, HID);

  k_normrope<<<(BATCH * S_LEN * (NH + NKV)) / 4, 256, 0, stream>>>(Qb, Kb, cosb, sinb, qw, kw);

  k_attn<<<dim3(S_LEN / 64, NH, BATCH), 256, 0, stream>>>(Qb, Kb, Vb, AOb);

  k_gemm_bt<float><<<dim3(16, 32), blk, 0, stream>>>(AOb, Wob, out, BATCH * S_LEN, HID, HID);
}

// Round 2
// 258.916 us; speedup vs baseline: 1.5024x; 1.5024x over previous
//
#include <hip/hip_runtime.h>
#include <stdint.h>

#define S_LEN 2048
#define BATCH 2
#define HID 2048
#define NH 16
#define NKV 8
#define HD 128
#define WINDOW 1024
#define SCALE 0.08838834764831845f
#define QKVW 4096

typedef unsigned short u16;
typedef unsigned int u32;
typedef __attribute__((ext_vector_type(8))) short short8;
typedef __attribute__((ext_vector_type(4))) float f32x4;
typedef __attribute__((ext_vector_type(16))) float f32x16;
typedef __attribute__((ext_vector_type(4))) u16 u16x4;

__device__ __forceinline__ u16 f2b(float f) {
  u32 u = __builtin_bit_cast(u32, f);
  return (u16)((u + 0x7fffu + ((u >> 16) & 1u)) >> 16);
}
__device__ __forceinline__ float b2f(u16 h) {
  u32 u = ((u32)h) << 16;
  return __builtin_bit_cast(float, u);
}
__device__ __forceinline__ u32 pk_bf16(float a, float b) {
  u32 d;
  asm("v_cvt_pk_bf16_f32 %0, %1, %2" : "=v"(d) : "v"(a), "v"(b));
  return d;
}

__device__ __forceinline__ void gload_lds16(const u16* g, u16* l) {
  __builtin_amdgcn_global_load_lds(
      (const __attribute__((address_space(1))) u32*)g,
      (__attribute__((address_space(3))) u32*)l, 16, 0, 0);
}

// ---------------- f32 -> bf16 convert ----------------
__global__ __launch_bounds__(256) void k_conv(const float* __restrict__ src,
                                              u16* __restrict__ dst, int n4) {
  int i = blockIdx.x * blockDim.x + threadIdx.x;
  int st = gridDim.x * blockDim.x;
  for (; i < n4; i += st) {
    f32x4 v = ((const f32x4*)src)[i];
    u16x4 o;
    o[0] = f2b(v[0]); o[1] = f2b(v[1]); o[2] = f2b(v[2]); o[3] = f2b(v[3]);
    ((u16x4*)dst)[i] = o;
  }
}

// ---------------- GEMM C = A * B^T ----------------
__device__ __forceinline__ void store_c(u16* C, long idx, float v) { C[idx] = f2b(v); }
__device__ __forceinline__ void store_c(float* C, long idx, float v) { C[idx] = v; }

template <typename OutT>
__global__ __launch_bounds__(256) void k_gemm_bt(const u16* __restrict__ A,
                                                 const u16* __restrict__ B,
                                                 OutT* __restrict__ C,
                                                 int M, int N, int K) {
  __shared__ u16 sA[128 * 32];
  __shared__ u16 sB[128 * 32];
  const int tid = threadIdx.x;
  const int lane = tid & 63;
  const int l15 = lane & 15;
  const int lg = lane >> 4;
  const int w = tid >> 6;
  const int wr = w >> 1;
  const int wc = w & 1;
  const long m0 = (long)blockIdx.y * 128;
  const long n0 = (long)blockIdx.x * 128;

  f32x4 acc[4][4];
  const f32x4 z4 = {0.f, 0.f, 0.f, 0.f};
#pragma unroll
  for (int i = 0; i < 4; ++i)
#pragma unroll
    for (int j = 0; j < 4; ++j) acc[i][j] = z4;

  const int c0 = tid, c1 = tid + 256;
  const u16* gA0 = A + (m0 + (c0 >> 2)) * K + (c0 & 3) * 8;
  const u16* gA1 = A + (m0 + (c1 >> 2)) * K + (c1 & 3) * 8;
  const u16* gB0 = B + (n0 + (c0 >> 2)) * K + (c0 & 3) * 8;
  const u16* gB1 = B + (n0 + (c1 >> 2)) * K + (c1 & 3) * 8;
  u16* lA0 = &sA[c0 * 8]; u16* lA1 = &sA[c1 * 8];
  u16* lB0 = &sB[c0 * 8]; u16* lB1 = &sB[c1 * 8];

  for (int k0 = 0; k0 < K; k0 += 32) {
    gload_lds16(gA0 + k0, lA0);
    gload_lds16(gA1 + k0, lA1);
    gload_lds16(gB0 + k0, lB0);
    gload_lds16(gB1 + k0, lB1);
    __syncthreads();
    short8 aF[4], bF[4];
#pragma unroll
    for (int i = 0; i < 4; ++i)
      aF[i] = *(const short8*)&sA[(wr * 64 + i * 16 + l15) * 32 + lg * 8];
#pragma unroll
    for (int j = 0; j < 4; ++j)
      bF[j] = *(const short8*)&sB[(wc * 64 + j * 16 + l15) * 32 + lg * 8];
#pragma unroll
    for (int i = 0; i < 4; ++i)
#pragma unroll
      for (int j = 0; j < 4; ++j)
        acc[i][j] = __builtin_amdgcn_mfma_f32_16x16x32_bf16(aF[i], bF[j], acc[i][j], 0, 0, 0);
    __syncthreads();
  }

#pragma unroll
  for (int i = 0; i < 4; ++i)
#pragma unroll
    for (int j = 0; j < 4; ++j)
#pragma unroll
      for (int r = 0; r < 4; ++r) {
        long row = m0 + wr * 64 + i * 16 + lg * 4 + r;
        long col = n0 + wc * 64 + j * 16 + l15;
        store_c(C, row * N + col, acc[i][j][r]);
      }
}

// ---------------- RMSNorm + RoPE (in place on fused QKV, bf16) ----------------
__global__ __launch_bounds__(256) void k_normrope(u16* __restrict__ QKV,
                                                  const float* __restrict__ cosb,
                                                  const float* __restrict__ sinb,
                                                  const float* __restrict__ qw,
                                                  const float* __restrict__ kw) {
  const int lane = threadIdx.x & 63;
  const int w = threadIdx.x >> 6;
  int row = blockIdx.x * 4 + w;
  const int nQ = BATCH * S_LEN * NH;
  u16* p;
  const float* nw;
  int tok;
  float sc;
  if (row < nQ) {
    tok = row >> 4;
    int h = row & 15;
    p = QKV + (long)tok * QKVW + h * HD;
    nw = qw;
    sc = SCALE;   // fold attention scaling into Q
  } else {
    int r2 = row - nQ;
    tok = r2 >> 3;
    int h = r2 & 7;
    p = QKV + (long)tok * QKVW + 2048 + h * HD;
    nw = kw;
    sc = 1.0f;
  }
  float x0 = b2f(p[lane]);
  float x1 = b2f(p[lane + 64]);
  float ss = x0 * x0 + x1 * x1;
#pragma unroll
  for (int mk = 1; mk < 64; mk <<= 1) ss += __shfl_xor(ss, mk, 64);
  float rinv = rsqrtf(ss * (1.0f / 128.0f) + 1e-6f);
  float y0 = x0 * rinv * nw[lane];
  float y1 = x1 * rinv * nw[lane + 64];
  const float* cp = cosb + (long)tok * HD;
  const float* sp = sinb + (long)tok * HD;
  float o0 = (y0 * cp[lane] - y1 * sp[lane]) * sc;
  float o1 = (y1 * cp[lane + 64] + y0 * sp[lane + 64]) * sc;
  p[lane] = f2b(o0);
  p[lane + 64] = f2b(o1);
}

// ---------------- Flash attention: 4 waves x 32 q-rows, KVBLK=64, 32x32x16 ----
// Swapped QK^T: S^T = mfma(A=K, B=Q)  -> lane owns q = lane&31, k per reg.
// Swapped PV:   O^T = mfma(A=V^T, B=P^T) -> lane keeps q = lane&31.
__global__ __launch_bounds__(256, 2) void k_attn(const u16* __restrict__ QKV,
                                                 u16* __restrict__ AO) {
  __shared__ u16 sK[64 * 128];    // unit(row,ch) = row*16 + (ch ^ (row&7)), 16B units
  __shared__ u16 sVT[64 * 128];   // unit(d,rg)  = d*8  + (rg ^ (d&7)),   16B = 8 k at fixed d
  const int tid = threadIdx.x;
  const int lane = tid & 63;
  const int l31 = lane & 31;
  const int hi = lane >> 5;
  const int w = tid >> 6;
  const int q0 = blockIdx.x * 128;
  const int h = blockIdx.y;
  const int b = blockIdx.z;
  const int kvh = h >> 1;
  const int qw0 = q0 + w * 32;
  const int iq = qw0 + l31;

  const long tokbase = (long)b * S_LEN;
  // Q fragments (B-operand): col=lane&31 -> q-row, k = hi*8+j per 16-d tile
  const u16* Qrow = QKV + (tokbase + qw0 + l31) * QKVW + h * HD;
  short8 qf[8];
#pragma unroll
  for (int dt = 0; dt < 8; ++dt) qf[dt] = *(const short8*)(Qrow + dt * 16 + hi * 8);

  f32x16 o[4];
#pragma unroll
  for (int n = 0; n < 4; ++n)
#pragma unroll
    for (int r = 0; r < 16; ++r) o[n][r] = 0.f;
  float m = 0.f, lsum = 0.f;

  const u16* Kbase = QKV + tokbase * QKVW + 2048 + kvh * HD;
  const u16* Vbase = QKV + tokbase * QKVW + 3072 + kvh * HD;

  // K staging: 1024 16B chunks; LDS linear in tid order, source inverse-swizzled
  int kc_row[4], kc_off[4];
  u16* kc_dst[4];
#pragma unroll
  for (int i = 0; i < 4; ++i) {
    const int c = tid + 256 * i;
    kc_row[i] = c >> 4;
    kc_off[i] = (((c & 15) ^ ((c >> 4) & 7))) * 8;
    kc_dst[i] = &sK[c * 8];
  }
  const int rp = tid & 31;        // V row-pair
  const int dc0 = tid >> 5;       // V d-chunk (and +8)
  const int rg_st = rp >> 2;

  int t_lo = q0 - (WINDOW - 1);
  t_lo = (t_lo < 0 ? 0 : t_lo) >> 6;
  const int t_hi = (q0 + 127) >> 6;

  for (int t = t_lo; t <= t_hi; ++t) {
    const int kv0 = t << 6;
#pragma unroll
    for (int i = 0; i < 4; ++i)
      gload_lds16(Kbase + (long)(kv0 + kc_row[i]) * QKVW + kc_off[i], kc_dst[i]);
#pragma unroll
    for (int i = 0; i < 2; ++i) {
      const int dc = dc0 + i * 8;
      const u16* vp = Vbase + (long)(kv0 + 2 * rp) * QKVW + dc * 8;
      short8 v0 = *(const short8*)vp;
      short8 v1 = *(const short8*)(vp + QKVW);
#pragma unroll
      for (int e = 0; e < 8; ++e) {
        const int d = dc * 8 + e;
        const int unit = d * 8 + (rg_st ^ (d & 7));
        ((u32*)sVT)[unit * 4 + (rp & 3)] = (u32)(u16)v0[e] | ((u32)(u16)v1[e] << 16);
      }
    }
    __syncthreads();

    const bool skipw = (kv0 > qw0 + 31) || (kv0 + 63 < qw0 - (WINDOW - 1));
    if (!skipw) {
      const bool full = (kv0 + 63 <= qw0) && ((qw0 + 31) - kv0 < WINDOW);
      f32x16 s0, s1;
#pragma unroll
      for (int r = 0; r < 16; ++r) { s0[r] = 0.f; s1[r] = 0.f; }
      const int rsw = l31 & 7;
#pragma unroll
      for (int dt = 0; dt < 8; ++dt) {
        const int ch = hi + 2 * dt;
        const short8 kf0 = *(const short8*)&sK[(l31 * 16 + (ch ^ rsw)) * 8];
        s0 = __builtin_amdgcn_mfma_f32_32x32x16_bf16(kf0, qf[dt], s0, 0, 0, 0);
        const short8 kf1 = *(const short8*)&sK[((l31 + 32) * 16 + (ch ^ rsw)) * 8];
        s1 = __builtin_amdgcn_mfma_f32_32x32x16_bf16(kf1, qf[dt], s1, 0, 0, 0);
      }
      float p[32];
#pragma unroll
      for (int r = 0; r < 16; ++r) { p[r] = s0[r]; p[16 + r] = s1[r]; }
      if (!full) {
#pragma unroll
        for (int r = 0; r < 32; ++r) {
          const int kk = kv0 + (r >> 4) * 32 + 4 * hi + (r & 3) + 8 * ((r >> 2) & 3);
          p[r] = ((u32)(iq - kk) < (u32)WINDOW) ? p[r] : -3.0e38f;
        }
      }
      float tm = p[0];
#pragma unroll
      for (int r = 1; r < 32; ++r) tm = fmaxf(tm, p[r]);
      tm = fmaxf(tm, __shfl_xor(tm, 32, 64));
      const float mn = fmaxf(m, tm);
      const float al = __expf(m - mn);
      m = mn;
      float rs = 0.f;
#pragma unroll
      for (int r = 0; r < 32; ++r) { p[r] = __expf(p[r] - mn); rs += p[r]; }
      rs += __shfl_xor(rs, 32, 64);
      lsum = lsum * al + rs;
#pragma unroll
      for (int n = 0; n < 4; ++n)
#pragma unroll
        for (int r = 0; r < 16; ++r) o[n][r] *= al;

      // P -> bf16 A/B-fragments via cvt_pk + permlane32_swap (guide T12 recipe)
      short8 pf[4];
#pragma unroll
      for (int ks = 0; ks < 4; ++ks) {
        const int bb = (ks >> 1) * 16 + (ks & 1) * 8;
        u32 a0 = pk_bf16(p[bb + 0], p[bb + 1]);
        u32 b0 = pk_bf16(p[bb + 4], p[bb + 5]);
        u32 a1 = pk_bf16(p[bb + 2], p[bb + 3]);
        u32 b1 = pk_bf16(p[bb + 6], p[bb + 7]);
        asm volatile("v_permlane32_swap_b32 %0, %1" : "+v"(a0), "+v"(b0));
        asm volatile("v_permlane32_swap_b32 %0, %1" : "+v"(a1), "+v"(b1));
        union { u32 u[4]; short8 s; } uu;
        uu.u[0] = a0; uu.u[1] = a1; uu.u[2] = b0; uu.u[3] = b1;
        pf[ks] = uu.s;
      }
      // PV: O^T += mfma(A=V^T, B=P^T)
#pragma unroll
      for (int dt = 0; dt < 4; ++dt) {
        const int d = l31 + 32 * dt;
        const int dsw = d & 7;
#pragma unroll
        for (int ks = 0; ks < 4; ++ks) {
          const int rg = ks * 2 + hi;
          const short8 vf = *(const short8*)&sVT[(d * 8 + (rg ^ dsw)) * 8];
          o[dt] = __builtin_amdgcn_mfma_f32_32x32x16_bf16(vf, pf[ks], o[dt], 0, 0, 0);
        }
      }
    }
    __syncthreads();
  }

  // Epilogue: transpose O^T via per-wave 4KB LDS region, coalesced bf16 stores
  __syncthreads();
  float* R = ((float*)sK) + w * 1024;
  const float rl = 1.0f / lsum;
  const int half = hi;
#pragma unroll
  for (int dt = 0; dt < 4; ++dt) {
#pragma unroll
    for (int r = 0; r < 16; ++r) {
      const int dp = 4 * hi + (r & 3) + 8 * (r >> 2);
      R[dp * 32 + (l31 ^ (4 * (dp & 7)))] = o[dt][r] * rl;
    }
    __syncthreads();
    union { u16 hh[16]; short8 s[2]; } U;
#pragma unroll
    for (int j = 0; j < 16; ++j) {
      const int dp = half * 16 + j;
      U.hh[j] = f2b(R[dp * 32 + (l31 ^ (4 * (dp & 7)))]);
    }
    u16* dst = AO + (tokbase + q0 + w * 32 + l31) * (NH * HD) + h * HD + dt * 32 + half * 16;
    *(short8*)dst = U.s[0];
    *(short8*)(dst + 8) = U.s[1];
    __syncthreads();
  }
}

// ---------------- launch ----------------
extern "C" void kernel_launch(void* const* d_in, const int* in_sizes, int n_in,
                              void* d_out, int out_size, void* d_ws, size_t ws_size,
                              hipStream_t stream) {
  const float* hs   = (const float*)d_in[0];
  const float* cosb = (const float*)d_in[1];
  const float* sinb = (const float*)d_in[2];
  const float* Wq   = (const float*)d_in[3];
  const float* Wk   = (const float*)d_in[4];
  const float* Wv   = (const float*)d_in[5];
  const float* Wo   = (const float*)d_in[6];
  const float* qw   = (const float*)d_in[7];
  const float* kw   = (const float*)d_in[8];
  float* out = (float*)d_out;

  const long SZ_X  = (long)BATCH * S_LEN * HID;   // 8M
  const long SZ_WQ = (long)NH * HD * HID;         // 4M
  const long SZ_WK = (long)NKV * HD * HID;        // 2M
  u16* Xb   = (u16*)d_ws;
  u16* Wqb  = Xb + SZ_X;                          // Wq,Wk,Wv contiguous => fused B
  u16* Wkb  = Wqb + SZ_WQ;
  u16* Wvb  = Wkb + SZ_WK;
  u16* Wob  = Wvb + SZ_WK;
  u16* QKVb = Wob + SZ_WQ;                        // [4096 tokens][4096]
  u16* AOb  = QKVb + (long)BATCH * S_LEN * QKVW;  // [4096 tokens][2048]

  k_conv<<<2048, 256, 0, stream>>>(hs, Xb, (int)(SZ_X / 4));
  k_conv<<<1024, 256, 0, stream>>>(Wq, Wqb, (int)(SZ_WQ / 4));
  k_conv<<<512, 256, 0, stream>>>(Wk, Wkb, (int)(SZ_WK / 4));
  k_conv<<<512, 256, 0, stream>>>(Wv, Wvb, (int)(SZ_WK / 4));
  k_conv<<<1024, 256, 0, stream>>>(Wo, Wob, (int)(SZ_WQ / 4));

  dim3 blk(256);
  // fused QKV projection: N = 4096 (cols 0-2047 Q, 2048-3071 K, 3072-4095 V)
  k_gemm_bt<u16><<<dim3(32, 32), blk, 0, stream>>>(Xb, Wqb, QKVb, BATCH * S_LEN, QKVW, HID);

  k_normrope<<<(BATCH * S_LEN * (NH + NKV)) / 4, 256, 0, stream>>>(QKVb, cosb, sinb, qw, kw);

  k_attn<<<dim3(S_LEN / 128, NH, BATCH), blk, 0, stream>>>(QKVb, AOb);

  k_gemm_bt<float><<<dim3(16, 32), blk, 0, stream>>>(AOb, Wob, out, BATCH * S_LEN, HID, HID);
}

// Round 3
// 240.221 us; speedup vs baseline: 1.6193x; 1.0778x over previous
//
#include <hip/hip_runtime.h>
#include <stdint.h>

#define S_LEN 2048
#define BATCH 2
#define HID 2048
#define NH 16
#define NKV 8
#define HD 128
#define WINDOW 1024
#define SCALE 0.08838834764831845f
#define QKVW 4096

typedef unsigned short u16;
typedef unsigned int u32;
typedef __attribute__((ext_vector_type(8))) short short8;
typedef __attribute__((ext_vector_type(4))) float f32x4;
typedef __attribute__((ext_vector_type(16))) float f32x16;
typedef __attribute__((ext_vector_type(4))) u16 u16x4;

__device__ __forceinline__ u16 f2b(float f) {
  u32 u = __builtin_bit_cast(u32, f);
  return (u16)((u + 0x7fffu + ((u >> 16) & 1u)) >> 16);
}
__device__ __forceinline__ float b2f(u16 h) {
  u32 u = ((u32)h) << 16;
  return __builtin_bit_cast(float, u);
}
__device__ __forceinline__ u32 pk_bf16(float a, float b) {
  u32 d;
  asm("v_cvt_pk_bf16_f32 %0, %1, %2" : "=v"(d) : "v"(a), "v"(b));
  return d;
}

__device__ __forceinline__ void gload_lds16(const u16* g, u16* l) {
  __builtin_amdgcn_global_load_lds(
      (const __attribute__((address_space(1))) u32*)g,
      (__attribute__((address_space(3))) u32*)l, 16, 0, 0);
}

template <int N>
__device__ __forceinline__ void wait_vm() {
  if constexpr (N == 0) asm volatile("s_waitcnt vmcnt(0)" ::: "memory");
  else if constexpr (N == 1) asm volatile("s_waitcnt vmcnt(1)" ::: "memory");
  else if constexpr (N == 2) asm volatile("s_waitcnt vmcnt(2)" ::: "memory");
  else if constexpr (N == 4) asm volatile("s_waitcnt vmcnt(4)" ::: "memory");
  else if constexpr (N == 8) asm volatile("s_waitcnt vmcnt(8)" ::: "memory");
}

// ---------------- f32 -> bf16 convert ----------------
__global__ __launch_bounds__(256) void k_conv(const float* __restrict__ src,
                                              u16* __restrict__ dst, int n4) {
  int i = blockIdx.x * blockDim.x + threadIdx.x;
  int st = gridDim.x * blockDim.x;
  for (; i < n4; i += st) {
    f32x4 v = ((const f32x4*)src)[i];
    u16x4 o;
    o[0] = f2b(v[0]); o[1] = f2b(v[1]); o[2] = f2b(v[2]); o[3] = f2b(v[3]);
    ((u16x4*)dst)[i] = o;
  }
}

__device__ __forceinline__ void store_c(u16* C, long idx, float v) { C[idx] = f2b(v); }
__device__ __forceinline__ void store_c(float* C, long idx, float v) { C[idx] = v; }

// ---------------- GEMM C = A * B^T : BMx256 tile, BK=64, counted-vmcnt phases ---
// A: M x K bf16 rm; B: N x K bf16 rm. 512 threads = 8 waves (2M x 4N).
// LDS [row][64] with chunk-XOR swizzle ch^(row&7); staging linear via
// global_load_lds with inverse-swizzled global source (rule 21).
template <int BM, typename OutT>
__global__ __launch_bounds__(512, 2) void k_gemm8p(const u16* __restrict__ A,
                                                   const u16* __restrict__ B,
                                                   OutT* __restrict__ C,
                                                   int M, int N, int K) {
  constexpr int MI = BM / 32;    // M-frags per wave
  constexpr int NP = MI / 2;     // phases per K-tile
  constexpr int MIDP = NP / 2;   // phase that first needs A-hi
  constexpr int LA = BM / 64;    // A chunk-loads per thread per tile
  constexpr int LAL = LA / 2;    // A-lo issues per thread
  constexpr int LB = 4;          // B chunk-loads per thread
  constexpr int HBH = BM / 32;   // lo regions per wave-block
  constexpr int ASZ = BM * 64;
  constexpr int BSZ = 256 * 64;

  __shared__ u16 sA[2 * ASZ];
  __shared__ u16 sB[2 * BSZ];

  const int tid = threadIdx.x;
  const int lane = tid & 63;
  const int w = tid >> 6;
  const int l15 = lane & 15;
  const int lg = lane >> 4;
  const int wm = w >> 2;
  const int wn = w & 3;

  // XCD-aware swizzle (nwg == 256, divisible by 8)
  const int gx = gridDim.x;
  const int nwg = gx * gridDim.y;
  const int flat = blockIdx.y * gx + blockIdx.x;
  const int tile = (flat & 7) * (nwg >> 3) + (flat >> 3);
  const long m0 = (long)(tile / gx) * BM;
  const long n0 = (long)(tile % gx) * 256;

  // staging descriptors
  const u16* bsrc[LB]; int bdo[LB];
#pragma unroll
  for (int j = 0; j < LB; ++j) {
    const int row0 = (w * 4 + j) * 8;
    const int row = row0 + (lane >> 3);
    const int lch = (lane & 7) ^ (row & 7);
    bsrc[j] = B + (n0 + row) * (long)K + lch * 8;
    bdo[j] = (row0 * 8 + lane) * 8;
  }
  const u16* asrcL[LAL]; int adoL[LAL];
  const u16* asrcH[LAL]; int adoH[LAL];
#pragma unroll
  for (int j = 0; j < LAL; ++j) {
    const int rr = j * 8 + w;
    const int wb = (rr >= HBH) ? 1 : 0;
    const int r0l = wb * (BM / 2) + (rr - wb * HBH) * 8;
    const int r0h = r0l + BM / 4;
    {
      const int row = r0l + (lane >> 3);
      const int lch = (lane & 7) ^ (row & 7);
      asrcL[j] = A + (m0 + row) * (long)K + lch * 8;
      adoL[j] = (r0l * 8 + lane) * 8;
    }
    {
      const int row = r0h + (lane >> 3);
      const int lch = (lane & 7) ^ (row & 7);
      asrcH[j] = A + (m0 + row) * (long)K + lch * 8;
      adoH[j] = (r0h * 8 + lane) * 8;
    }
  }

  f32x4 acc[MI][4];
  const f32x4 z4 = {0.f, 0.f, 0.f, 0.f};
#pragma unroll
  for (int i = 0; i < MI; ++i)
#pragma unroll
    for (int j = 0; j < 4; ++j) acc[i][j] = z4;

  const int NT = K >> 6;
  // prologue: tile 0 -> buffer 0 (issue order B, A-lo, A-hi matters for vmcnt)
#pragma unroll
  for (int j = 0; j < LB; ++j) gload_lds16(bsrc[j], &sB[bdo[j]]);
#pragma unroll
  for (int j = 0; j < LAL; ++j) gload_lds16(asrcL[j], &sA[adoL[j]]);
#pragma unroll
  for (int j = 0; j < LAL; ++j) gload_lds16(asrcH[j], &sA[adoH[j]]);

  const int abase = wm * (BM / 2) + l15;
  const int asw = abase & 7;
  const int bbase = wn * 64 + l15;
  const int bsw = bbase & 7;

  short8 bf[4][2];
  int cur = 0;

  for (int t = 0; t < NT; ++t) {
    const int nxt = cur ^ 1;
    const bool pre = (t + 1 < NT);
    const int koff = (t + 1) * 64;
#pragma unroll
    for (int p = 0; p < NP; ++p) {
      if (p == 0) {
        wait_vm<LA / 2>();            // B(t)+A-lo(t) landed; A-hi(t) still flying
        __builtin_amdgcn_sched_barrier(0);
        __builtin_amdgcn_s_barrier();
        if (pre) {
#pragma unroll
          for (int j = 0; j < LB; ++j)
            gload_lds16(bsrc[j] + koff, &sB[nxt * BSZ + bdo[j]]);
        }
#pragma unroll
        for (int ni = 0; ni < 4; ++ni)
#pragma unroll
          for (int kk = 0; kk < 2; ++kk)
            bf[ni][kk] = *(const short8*)
                &sB[cur * BSZ + (bbase + ni * 16) * 64 + ((kk * 4 + lg) ^ bsw) * 8];
      } else if (p == MIDP) {
        if (pre) wait_vm<(NP == 2) ? 4 : 8>();  // drain A-hi(t) only
        else     wait_vm<0>();
        __builtin_amdgcn_sched_barrier(0);
        __builtin_amdgcn_s_barrier();
        if (NP == 2 && pre) {
#pragma unroll
          for (int j = 0; j < LAL; ++j)
            gload_lds16(asrcL[j] + koff, &sA[nxt * ASZ + adoL[j]]);
#pragma unroll
          for (int j = 0; j < LAL; ++j)
            gload_lds16(asrcH[j] + koff, &sA[nxt * ASZ + adoH[j]]);
        }
      } else {
        __builtin_amdgcn_s_barrier();
        if (p == 1 && pre) {          // NP==4 path
#pragma unroll
          for (int j = 0; j < LAL; ++j)
            gload_lds16(asrcL[j] + koff, &sA[nxt * ASZ + adoL[j]]);
#pragma unroll
          for (int j = 0; j < LAL; ++j)
            gload_lds16(asrcH[j] + koff, &sA[nxt * ASZ + adoH[j]]);
        }
      }
      short8 af[2][2];
#pragma unroll
      for (int i = 0; i < 2; ++i)
#pragma unroll
        for (int kk = 0; kk < 2; ++kk)
          af[i][kk] = *(const short8*)
              &sA[cur * ASZ + (abase + (2 * p + i) * 16) * 64 + ((kk * 4 + lg) ^ asw) * 8];
      __builtin_amdgcn_s_setprio(1);
#pragma unroll
      for (int i = 0; i < 2; ++i)
#pragma unroll
        for (int ni = 0; ni < 4; ++ni)
#pragma unroll
          for (int kk = 0; kk < 2; ++kk)
            acc[2 * p + i][ni] = __builtin_amdgcn_mfma_f32_16x16x32_bf16(
                af[i][kk], bf[ni][kk], acc[2 * p + i][ni], 0, 0, 0);
      __builtin_amdgcn_s_setprio(0);
    }
    cur = nxt;
  }

#pragma unroll
  for (int mi = 0; mi < MI; ++mi)
#pragma unroll
    for (int ni = 0; ni < 4; ++ni)
#pragma unroll
      for (int r = 0; r < 4; ++r) {
        long row = m0 + wm * (BM / 2) + mi * 16 + lg * 4 + r;
        long col = n0 + wn * 64 + ni * 16 + l15;
        store_c(C, row * (long)N + col, acc[mi][ni][r]);
      }
}

// ---------------- RMSNorm + RoPE (in place on fused QKV, bf16) ----------------
__global__ __launch_bounds__(256) void k_normrope(u16* __restrict__ QKV,
                                                  const float* __restrict__ cosb,
                                                  const float* __restrict__ sinb,
                                                  const float* __restrict__ qw,
                                                  const float* __restrict__ kw) {
  const int lane = threadIdx.x & 63;
  const int w = threadIdx.x >> 6;
  int row = blockIdx.x * 4 + w;
  const int nQ = BATCH * S_LEN * NH;
  u16* p;
  const float* nw;
  int tok;
  float sc;
  if (row < nQ) {
    tok = row >> 4;
    int h = row & 15;
    p = QKV + (long)tok * QKVW + h * HD;
    nw = qw;
    sc = SCALE;
  } else {
    int r2 = row - nQ;
    tok = r2 >> 3;
    int h = r2 & 7;
    p = QKV + (long)tok * QKVW + 2048 + h * HD;
    nw = kw;
    sc = 1.0f;
  }
  float x0 = b2f(p[lane]);
  float x1 = b2f(p[lane + 64]);
  float ss = x0 * x0 + x1 * x1;
#pragma unroll
  for (int mk = 1; mk < 64; mk <<= 1) ss += __shfl_xor(ss, mk, 64);
  float rinv = rsqrtf(ss * (1.0f / 128.0f) + 1e-6f);
  float y0 = x0 * rinv * nw[lane];
  float y1 = x1 * rinv * nw[lane + 64];
  const float* cp = cosb + (long)tok * HD;
  const float* sp = sinb + (long)tok * HD;
  float o0 = (y0 * cp[lane] - y1 * sp[lane]) * sc;
  float o1 = (y1 * cp[lane + 64] + y0 * sp[lane + 64]) * sc;
  p[lane] = f2b(o0);
  p[lane + 64] = f2b(o1);
}

// ---------------- Flash attention (unchanged from round 2) ----------------
__global__ __launch_bounds__(256, 2) void k_attn(const u16* __restrict__ QKV,
                                                 u16* __restrict__ AO) {
  __shared__ u16 sK[64 * 128];
  __shared__ u16 sVT[64 * 128];
  const int tid = threadIdx.x;
  const int lane = tid & 63;
  const int l31 = lane & 31;
  const int hi = lane >> 5;
  const int w = tid >> 6;
  const int q0 = blockIdx.x * 128;
  const int h = blockIdx.y;
  const int b = blockIdx.z;
  const int kvh = h >> 1;
  const int qw0 = q0 + w * 32;
  const int iq = qw0 + l31;

  const long tokbase = (long)b * S_LEN;
  const u16* Qrow = QKV + (tokbase + qw0 + l31) * QKVW + h * HD;
  short8 qf[8];
#pragma unroll
  for (int dt = 0; dt < 8; ++dt) qf[dt] = *(const short8*)(Qrow + dt * 16 + hi * 8);

  f32x16 o[4];
#pragma unroll
  for (int n = 0; n < 4; ++n)
#pragma unroll
    for (int r = 0; r < 16; ++r) o[n][r] = 0.f;
  float m = 0.f, lsum = 0.f;

  const u16* Kbase = QKV + tokbase * QKVW + 2048 + kvh * HD;
  const u16* Vbase = QKV + tokbase * QKVW + 3072 + kvh * HD;

  int kc_row[4], kc_off[4];
  u16* kc_dst[4];
#pragma unroll
  for (int i = 0; i < 4; ++i) {
    const int c = tid + 256 * i;
    kc_row[i] = c >> 4;
    kc_off[i] = (((c & 15) ^ ((c >> 4) & 7))) * 8;
    kc_dst[i] = &sK[c * 8];
  }
  const int rp = tid & 31;
  const int dc0 = tid >> 5;
  const int rg_st = rp >> 2;

  int t_lo = q0 - (WINDOW - 1);
  t_lo = (t_lo < 0 ? 0 : t_lo) >> 6;
  const int t_hi = (q0 + 127) >> 6;

  for (int t = t_lo; t <= t_hi; ++t) {
    const int kv0 = t << 6;
#pragma unroll
    for (int i = 0; i < 4; ++i)
      gload_lds16(Kbase + (long)(kv0 + kc_row[i]) * QKVW + kc_off[i], kc_dst[i]);
#pragma unroll
    for (int i = 0; i < 2; ++i) {
      const int dc = dc0 + i * 8;
      const u16* vp = Vbase + (long)(kv0 + 2 * rp) * QKVW + dc * 8;
      short8 v0 = *(const short8*)vp;
      short8 v1 = *(const short8*)(vp + QKVW);
#pragma unroll
      for (int e = 0; e < 8; ++e) {
        const int d = dc * 8 + e;
        const int unit = d * 8 + (rg_st ^ (d & 7));
        ((u32*)sVT)[unit * 4 + (rp & 3)] = (u32)(u16)v0[e] | ((u32)(u16)v1[e] << 16);
      }
    }
    __syncthreads();

    const bool skipw = (kv0 > qw0 + 31) || (kv0 + 63 < qw0 - (WINDOW - 1));
    if (!skipw) {
      const bool full = (kv0 + 63 <= qw0) && ((qw0 + 31) - kv0 < WINDOW);
      f32x16 s0, s1;
#pragma unroll
      for (int r = 0; r < 16; ++r) { s0[r] = 0.f; s1[r] = 0.f; }
      const int rsw = l31 & 7;
#pragma unroll
      for (int dt = 0; dt < 8; ++dt) {
        const int ch = hi + 2 * dt;
        const short8 kf0 = *(const short8*)&sK[(l31 * 16 + (ch ^ rsw)) * 8];
        s0 = __builtin_amdgcn_mfma_f32_32x32x16_bf16(kf0, qf[dt], s0, 0, 0, 0);
        const short8 kf1 = *(const short8*)&sK[((l31 + 32) * 16 + (ch ^ rsw)) * 8];
        s1 = __builtin_amdgcn_mfma_f32_32x32x16_bf16(kf1, qf[dt], s1, 0, 0, 0);
      }
      float p[32];
#pragma unroll
      for (int r = 0; r < 16; ++r) { p[r] = s0[r]; p[16 + r] = s1[r]; }
      if (!full) {
#pragma unroll
        for (int r = 0; r < 32; ++r) {
          const int kk = kv0 + (r >> 4) * 32 + 4 * hi + (r & 3) + 8 * ((r >> 2) & 3);
          p[r] = ((u32)(iq - kk) < (u32)WINDOW) ? p[r] : -3.0e38f;
        }
      }
      float tm = p[0];
#pragma unroll
      for (int r = 1; r < 32; ++r) tm = fmaxf(tm, p[r]);
      tm = fmaxf(tm, __shfl_xor(tm, 32, 64));
      const float mn = fmaxf(m, tm);
      const float al = __expf(m - mn);
      m = mn;
      float rs = 0.f;
#pragma unroll
      for (int r = 0; r < 32; ++r) { p[r] = __expf(p[r] - mn); rs += p[r]; }
      rs += __shfl_xor(rs, 32, 64);
      lsum = lsum * al + rs;
#pragma unroll
      for (int n = 0; n < 4; ++n)
#pragma unroll
        for (int r = 0; r < 16; ++r) o[n][r] *= al;

      short8 pf[4];
#pragma unroll
      for (int ks = 0; ks < 4; ++ks) {
        const int bb = (ks >> 1) * 16 + (ks & 1) * 8;
        u32 a0 = pk_bf16(p[bb + 0], p[bb + 1]);
        u32 b0 = pk_bf16(p[bb + 4], p[bb + 5]);
        u32 a1 = pk_bf16(p[bb + 2], p[bb + 3]);
        u32 b1 = pk_bf16(p[bb + 6], p[bb + 7]);
        asm volatile("v_permlane32_swap_b32 %0, %1" : "+v"(a0), "+v"(b0));
        asm volatile("v_permlane32_swap_b32 %0, %1" : "+v"(a1), "+v"(b1));
        union { u32 u[4]; short8 s; } uu;
        uu.u[0] = a0; uu.u[1] = a1; uu.u[2] = b0; uu.u[3] = b1;
        pf[ks] = uu.s;
      }
#pragma unroll
      for (int dt = 0; dt < 4; ++dt) {
        const int d = l31 + 32 * dt;
        const int dsw = d & 7;
#pragma unroll
        for (int ks = 0; ks < 4; ++ks) {
          const int rg = ks * 2 + hi;
          const short8 vf = *(const short8*)&sVT[(d * 8 + (rg ^ dsw)) * 8];
          o[dt] = __builtin_amdgcn_mfma_f32_32x32x16_bf16(vf, pf[ks], o[dt], 0, 0, 0);
        }
      }
    }
    __syncthreads();
  }

  __syncthreads();
  float* R = ((float*)sK) + w * 1024;
  const float rl = 1.0f / lsum;
  const int half = hi;
#pragma unroll
  for (int dt = 0; dt < 4; ++dt) {
#pragma unroll
    for (int r = 0; r < 16; ++r) {
      const int dp = 4 * hi + (r & 3) + 8 * (r >> 2);
      R[dp * 32 + (l31 ^ (4 * (dp & 7)))] = o[dt][r] * rl;
    }
    __syncthreads();
    union { u16 hh[16]; short8 s[2]; } U;
#pragma unroll
    for (int j = 0; j < 16; ++j) {
      const int dp = half * 16 + j;
      U.hh[j] = f2b(R[dp * 32 + (l31 ^ (4 * (dp & 7)))]);
    }
    u16* dst = AO + (tokbase + q0 + w * 32 + l31) * (NH * HD) + h * HD + dt * 32 + half * 16;
    *(short8*)dst = U.s[0];
    *(short8*)(dst + 8) = U.s[1];
    __syncthreads();
  }
}

// ---------------- launch ----------------
extern "C" void kernel_launch(void* const* d_in, const int* in_sizes, int n_in,
                              void* d_out, int out_size, void* d_ws, size_t ws_size,
                              hipStream_t stream) {
  const float* hs   = (const float*)d_in[0];
  const float* cosb = (const float*)d_in[1];
  const float* sinb = (const float*)d_in[2];
  const float* Wq   = (const float*)d_in[3];
  const float* Wk   = (const float*)d_in[4];
  const float* Wv   = (const float*)d_in[5];
  const float* Wo   = (const float*)d_in[6];
  const float* qw   = (const float*)d_in[7];
  const float* kw   = (const float*)d_in[8];
  float* out = (float*)d_out;

  const long SZ_X  = (long)BATCH * S_LEN * HID;
  const long SZ_WQ = (long)NH * HD * HID;
  const long SZ_WK = (long)NKV * HD * HID;
  u16* Xb   = (u16*)d_ws;
  u16* Wqb  = Xb + SZ_X;
  u16* Wkb  = Wqb + SZ_WQ;
  u16* Wvb  = Wkb + SZ_WK;
  u16* Wob  = Wvb + SZ_WK;
  u16* QKVb = Wob + SZ_WQ;
  u16* AOb  = QKVb + (long)BATCH * S_LEN * QKVW;

  k_conv<<<2048, 256, 0, stream>>>(hs, Xb, (int)(SZ_X / 4));
  k_conv<<<1024, 256, 0, stream>>>(Wq, Wqb, (int)(SZ_WQ / 4));
  k_conv<<<512, 256, 0, stream>>>(Wk, Wkb, (int)(SZ_WK / 4));
  k_conv<<<512, 256, 0, stream>>>(Wv, Wvb, (int)(SZ_WK / 4));
  k_conv<<<1024, 256, 0, stream>>>(Wo, Wob, (int)(SZ_WQ / 4));

  // fused QKV projection: 4096 x 4096 x 2048, 256 blocks (1/CU)
  k_gemm8p<256, u16><<<dim3(16, 16), 512, 0, stream>>>(
      Xb, Wqb, QKVb, BATCH * S_LEN, QKVW, HID);

  k_normrope<<<(BATCH * S_LEN * (NH + NKV)) / 4, 256, 0, stream>>>(QKVb, cosb, sinb, qw, kw);

  k_attn<<<dim3(S_LEN / 128, NH, BATCH), 256, 0, stream>>>(QKVb, AOb);

  // output projection: 4096 x 2048 x 2048, BM=128 -> 256 blocks (1/CU)
  k_gemm8p<128, float><<<dim3(8, 32), 512, 0, stream>>>(
      AOb, Wob, out, BATCH * S_LEN, HID, HID);
}

// Round 4
// 232.393 us; speedup vs baseline: 1.6739x; 1.0337x over previous
//
#include <hip/hip_runtime.h>
#include <stdint.h>

#define S_LEN 2048
#define BATCH 2
#define HID 2048
#define NH 16
#define NKV 8
#define HD 128
#define WINDOW 1024
#define SCALE 0.08838834764831845f
#define QKVW 4096

typedef unsigned short u16;
typedef unsigned int u32;
typedef __attribute__((ext_vector_type(8))) short short8;
typedef __attribute__((ext_vector_type(4))) float f32x4;
typedef __attribute__((ext_vector_type(16))) float f32x16;
typedef __attribute__((ext_vector_type(4))) u16 u16x4;

__device__ __forceinline__ u16 f2b(float f) {
  u32 u = __builtin_bit_cast(u32, f);
  return (u16)((u + 0x7fffu + ((u >> 16) & 1u)) >> 16);
}
__device__ __forceinline__ float b2f(u16 h) {
  u32 u = ((u32)h) << 16;
  return __builtin_bit_cast(float, u);
}
__device__ __forceinline__ u32 pk_bf16(float a, float b) {
  u32 d;
  asm("v_cvt_pk_bf16_f32 %0, %1, %2" : "=v"(d) : "v"(a), "v"(b));
  return d;
}

__device__ __forceinline__ void gload_lds16(const u16* g, u16* l) {
  __builtin_amdgcn_global_load_lds(
      (const __attribute__((address_space(1))) u32*)g,
      (__attribute__((address_space(3))) u32*)l, 16, 0, 0);
}

template <int N>
__device__ __forceinline__ void wait_vm() {
  if constexpr (N == 0) asm volatile("s_waitcnt vmcnt(0)" ::: "memory");
  else if constexpr (N == 2) asm volatile("s_waitcnt vmcnt(2)" ::: "memory");
  else if constexpr (N == 4) asm volatile("s_waitcnt vmcnt(4)" ::: "memory");
}

// ---------------- f32 -> bf16 convert ----------------
__global__ __launch_bounds__(256) void k_conv(const float* __restrict__ src,
                                              u16* __restrict__ dst, int n4) {
  int i = blockIdx.x * blockDim.x + threadIdx.x;
  int st = gridDim.x * blockDim.x;
  for (; i < n4; i += st) {
    f32x4 v = ((const f32x4*)src)[i];
    u16x4 o;
    o[0] = f2b(v[0]); o[1] = f2b(v[1]); o[2] = f2b(v[2]); o[3] = f2b(v[3]);
    ((u16x4*)dst)[i] = o;
  }
}

__device__ __forceinline__ void store_c(u16* C, long idx, float v) { C[idx] = f2b(v); }
__device__ __forceinline__ void store_c(float* C, long idx, float v) { C[idx] = v; }

// ---- GEMM C = A*B^T, 256x256 tile, BK=64, 4-phase half-tile pipeline (m201 port)
// Half-tiles: A-h = interleaved 64-row blocks; B-h = interleaved 32-row blocks,
// so each wave's phase quadrant lives entirely in one half. Issue order per
// tile {A0,B0,B1,A1}, one half per phase; counted vmcnt(4) at phases 0,1,3.
#define LOADAF(MB)                                                          \
  _Pragma("unroll") for (int i_ = 0; i_ < 4; ++i_) {                        \
    af[i_][0] = *(const short8*)&sA[cur][arow + ((MB) + i_) * 1024 + akc0]; \
    af[i_][1] = *(const short8*)&sA[cur][arow + ((MB) + i_) * 1024 + akc1]; \
  }
#define LOADBF(NB)                                                          \
  _Pragma("unroll") for (int j_ = 0; j_ < 2; ++j_) {                        \
    bf[j_][0] = *(const short8*)&sB[cur][brow + ((NB) + j_) * 1024 + akc0]; \
    bf[j_][1] = *(const short8*)&sB[cur][brow + ((NB) + j_) * 1024 + akc1]; \
  }
#define STAGE_A(H)                                                    \
  gload_lds16(Abase + aOff[H][0] + koff, &sA[nxt][aDst[H][0]]);       \
  gload_lds16(Abase + aOff[H][1] + koff, &sA[nxt][aDst[H][1]]);
#define STAGE_B(H)                                                    \
  gload_lds16(Bbase + bOff[H][0] + koff, &sB[nxt][bDst[H][0]]);       \
  gload_lds16(Bbase + bOff[H][1] + koff, &sB[nxt][bDst[H][1]]);
#define MFMAQ(MI0, NI0)                                                         \
  __builtin_amdgcn_s_setprio(1);                                                \
  _Pragma("unroll") for (int i_ = 0; i_ < 4; ++i_) {                            \
    _Pragma("unroll") for (int j_ = 0; j_ < 2; ++j_) {                          \
      acc[(MI0) + i_][(NI0) + j_] = __builtin_amdgcn_mfma_f32_16x16x32_bf16(    \
          af[i_][0], bf[j_][0], acc[(MI0) + i_][(NI0) + j_], 0, 0, 0);          \
      acc[(MI0) + i_][(NI0) + j_] = __builtin_amdgcn_mfma_f32_16x16x32_bf16(    \
          af[i_][1], bf[j_][1], acc[(MI0) + i_][(NI0) + j_], 0, 0, 0);          \
    }                                                                           \
  }                                                                             \
  __builtin_amdgcn_s_setprio(0);
#define OPEN_MFMA()                                      \
  __builtin_amdgcn_sched_barrier(0);                     \
  __builtin_amdgcn_s_barrier();                          \
  asm volatile("s_waitcnt lgkmcnt(0)" ::: "memory");     \
  __builtin_amdgcn_sched_barrier(0);

template <typename OutT>
__global__ __launch_bounds__(512, 1) void k_gemm4p(const u16* __restrict__ A,
                                                   const u16* __restrict__ B,
                                                   OutT* __restrict__ C,
                                                   int M, int N, int K) {
  __shared__ u16 sA[2][256 * 64];
  __shared__ u16 sB[2][256 * 64];
  const int tid = threadIdx.x;
  const int lane = tid & 63;
  const int w = tid >> 6;
  const int l15 = lane & 15;
  const int lg = lane >> 4;
  const int wm = w >> 2;
  const int wn = w & 3;
  const int sw = l15 & 7;

  const int gx = gridDim.x;
  const int nwg = gx * gridDim.y;
  const int flat = blockIdx.y * gx + blockIdx.x;
  const int tile = (flat & 7) * (nwg >> 3) + (flat >> 3);
  const long m0 = (long)(tile / gx) * 256;
  const long n0 = (long)(tile % gx) * 256;

  const u16* Abase = A + m0 * K;
  const u16* Bbase = B + n0 * K;

  int aOff[2][2], aDst[2][2], bOff[2][2], bDst[2][2];
#pragma unroll
  for (int h = 0; h < 2; ++h)
#pragma unroll
    for (int i = 0; i < 2; ++i) {
      const int c = tid + i * 512;
      const int lr = c >> 3, chs = c & 7;
      const int grA = ((lr >> 6) << 7) + (h << 6) + (lr & 63);
      aOff[h][i] = grA * K + (chs ^ (grA & 7)) * 8;
      aDst[h][i] = grA * 64 + chs * 8;
      const int grB = ((lr >> 5) << 6) + (h << 5) + (lr & 31);
      bOff[h][i] = grB * K + (chs ^ (grB & 7)) * 8;
      bDst[h][i] = grB * 64 + chs * 8;
    }

  f32x4 acc[8][4];
  const f32x4 z4 = {0.f, 0.f, 0.f, 0.f};
#pragma unroll
  for (int i = 0; i < 8; ++i)
#pragma unroll
    for (int j = 0; j < 4; ++j) acc[i][j] = z4;

  const int arow = (wm * 128 + l15) * 64;
  const int brow = (wn * 64 + l15) * 64;
  const int akc0 = (lg ^ sw) * 8;
  const int akc1 = ((4 + lg) ^ sw) * 8;

  const int NT = K >> 6;
  int cur = 0;
  short8 af[4][2], bf[2][2];

  // prologue: tile 0 into buf 0, issue order = consumption order
  {
    const int nxt = 0, koff = 0;
    STAGE_A(0); STAGE_B(0); STAGE_B(1); STAGE_A(1);
  }
  wait_vm<4>();                    // A-h0(0), B-h0(0) landed
  __builtin_amdgcn_s_barrier();

  for (int t = 0; t < NT - 1; ++t) {
    const int nxt = cur ^ 1;
    const int koff = (t + 1) * 64;
    // ph0: Q(m-lo, n-lo)
    LOADAF(0) LOADBF(0)
    STAGE_A(0)
    wait_vm<4>();                  // drain B-h1(t)
    OPEN_MFMA()
    MFMAQ(0, 0)
    __builtin_amdgcn_s_barrier();
    // ph1: Q(m-lo, n-hi)
    LOADBF(2)
    STAGE_B(0)
    wait_vm<4>();                  // drain A-h1(t)
    OPEN_MFMA()
    MFMAQ(0, 2)
    __builtin_amdgcn_s_barrier();
    // ph2: Q(m-hi, n-hi)
    LOADAF(4)
    STAGE_B(1)
    OPEN_MFMA()
    MFMAQ(4, 2)
    __builtin_amdgcn_s_barrier();
    // ph3: Q(m-hi, n-lo)
    LOADBF(0)
    STAGE_A(1)
    wait_vm<4>();                  // drain A-h0(t+1), B-h0(t+1)
    OPEN_MFMA()
    MFMAQ(4, 0)
    __builtin_amdgcn_s_barrier();
    cur = nxt;
  }
  // final tile: no staging; residual waits 2 / 0
  {
    LOADAF(0) LOADBF(0)
    wait_vm<2>();                  // drain B-h1
    OPEN_MFMA()
    MFMAQ(0, 0)
    __builtin_amdgcn_s_barrier();
    LOADBF(2)
    wait_vm<0>();                  // drain A-h1
    OPEN_MFMA()
    MFMAQ(0, 2)
    __builtin_amdgcn_s_barrier();
    LOADAF(4)
    OPEN_MFMA()
    MFMAQ(4, 2)
    __builtin_amdgcn_s_barrier();
    LOADBF(0)
    OPEN_MFMA()
    MFMAQ(4, 0)
    __builtin_amdgcn_s_barrier();
  }

#pragma unroll
  for (int mi = 0; mi < 8; ++mi)
#pragma unroll
    for (int ni = 0; ni < 4; ++ni)
#pragma unroll
      for (int r = 0; r < 4; ++r) {
        long row = m0 + wm * 128 + mi * 16 + lg * 4 + r;
        long col = n0 + wn * 64 + ni * 16 + l15;
        store_c(C, row * (long)N + col, acc[mi][ni][r]);
      }
}

// ---------------- RMSNorm + RoPE (in place on fused QKV, bf16) ----------------
__global__ __launch_bounds__(256) void k_normrope(u16* __restrict__ QKV,
                                                  const float* __restrict__ cosb,
                                                  const float* __restrict__ sinb,
                                                  const float* __restrict__ qw,
                                                  const float* __restrict__ kw) {
  const int lane = threadIdx.x & 63;
  const int w = threadIdx.x >> 6;
  int row = blockIdx.x * 4 + w;
  const int nQ = BATCH * S_LEN * NH;
  u16* p;
  const float* nw;
  int tok;
  float sc;
  if (row < nQ) {
    tok = row >> 4;
    int h = row & 15;
    p = QKV + (long)tok * QKVW + h * HD;
    nw = qw;
    sc = SCALE;
  } else {
    int r2 = row - nQ;
    tok = r2 >> 3;
    int h = r2 & 7;
    p = QKV + (long)tok * QKVW + 2048 + h * HD;
    nw = kw;
    sc = 1.0f;
  }
  float x0 = b2f(p[lane]);
  float x1 = b2f(p[lane + 64]);
  float ss = x0 * x0 + x1 * x1;
#pragma unroll
  for (int mk = 1; mk < 64; mk <<= 1) ss += __shfl_xor(ss, mk, 64);
  float rinv = rsqrtf(ss * (1.0f / 128.0f) + 1e-6f);
  float y0 = x0 * rinv * nw[lane];
  float y1 = x1 * rinv * nw[lane + 64];
  const float* cp = cosb + (long)tok * HD;
  const float* sp = sinb + (long)tok * HD;
  float o0 = (y0 * cp[lane] - y1 * sp[lane]) * sc;
  float o1 = (y1 * cp[lane + 64] + y0 * sp[lane + 64]) * sc;
  p[lane] = f2b(o0);
  p[lane + 64] = f2b(o1);
}

// ---------------- Flash attention (unchanged) ----------------
__global__ __launch_bounds__(256, 2) void k_attn(const u16* __restrict__ QKV,
                                                 u16* __restrict__ AO) {
  __shared__ u16 sK[64 * 128];
  __shared__ u16 sVT[64 * 128];
  const int tid = threadIdx.x;
  const int lane = tid & 63;
  const int l31 = lane & 31;
  const int hi = lane >> 5;
  const int w = tid >> 6;
  const int q0 = blockIdx.x * 128;
  const int h = blockIdx.y;
  const int b = blockIdx.z;
  const int kvh = h >> 1;
  const int qw0 = q0 + w * 32;
  const int iq = qw0 + l31;

  const long tokbase = (long)b * S_LEN;
  const u16* Qrow = QKV + (tokbase + qw0 + l31) * QKVW + h * HD;
  short8 qf[8];
#pragma unroll
  for (int dt = 0; dt < 8; ++dt) qf[dt] = *(const short8*)(Qrow + dt * 16 + hi * 8);

  f32x16 o[4];
#pragma unroll
  for (int n = 0; n < 4; ++n)
#pragma unroll
    for (int r = 0; r < 16; ++r) o[n][r] = 0.f;
  float m = 0.f, lsum = 0.f;

  const u16* Kbase = QKV + tokbase * QKVW + 2048 + kvh * HD;
  const u16* Vbase = QKV + tokbase * QKVW + 3072 + kvh * HD;

  int kc_row[4], kc_off[4];
  u16* kc_dst[4];
#pragma unroll
  for (int i = 0; i < 4; ++i) {
    const int c = tid + 256 * i;
    kc_row[i] = c >> 4;
    kc_off[i] = (((c & 15) ^ ((c >> 4) & 7))) * 8;
    kc_dst[i] = &sK[c * 8];
  }
  const int rp = tid & 31;
  const int dc0 = tid >> 5;
  const int rg_st = rp >> 2;

  int t_lo = q0 - (WINDOW - 1);
  t_lo = (t_lo < 0 ? 0 : t_lo) >> 6;
  const int t_hi = (q0 + 127) >> 6;

  for (int t = t_lo; t <= t_hi; ++t) {
    const int kv0 = t << 6;
#pragma unroll
    for (int i = 0; i < 4; ++i)
      gload_lds16(Kbase + (long)(kv0 + kc_row[i]) * QKVW + kc_off[i], kc_dst[i]);
#pragma unroll
    for (int i = 0; i < 2; ++i) {
      const int dc = dc0 + i * 8;
      const u16* vp = Vbase + (long)(kv0 + 2 * rp) * QKVW + dc * 8;
      short8 v0 = *(const short8*)vp;
      short8 v1 = *(const short8*)(vp + QKVW);
#pragma unroll
      for (int e = 0; e < 8; ++e) {
        const int d = dc * 8 + e;
        const int unit = d * 8 + (rg_st ^ (d & 7));
        ((u32*)sVT)[unit * 4 + (rp & 3)] = (u32)(u16)v0[e] | ((u32)(u16)v1[e] << 16);
      }
    }
    __syncthreads();

    const bool skipw = (kv0 > qw0 + 31) || (kv0 + 63 < qw0 - (WINDOW - 1));
    if (!skipw) {
      const bool full = (kv0 + 63 <= qw0) && ((qw0 + 31) - kv0 < WINDOW);
      f32x16 s0, s1;
#pragma unroll
      for (int r = 0; r < 16; ++r) { s0[r] = 0.f; s1[r] = 0.f; }
      const int rsw = l31 & 7;
#pragma unroll
      for (int dt = 0; dt < 8; ++dt) {
        const int ch = hi + 2 * dt;
        const short8 kf0 = *(const short8*)&sK[(l31 * 16 + (ch ^ rsw)) * 8];
        s0 = __builtin_amdgcn_mfma_f32_32x32x16_bf16(kf0, qf[dt], s0, 0, 0, 0);
        const short8 kf1 = *(const short8*)&sK[((l31 + 32) * 16 + (ch ^ rsw)) * 8];
        s1 = __builtin_amdgcn_mfma_f32_32x32x16_bf16(kf1, qf[dt], s1, 0, 0, 0);
      }
      float p[32];
#pragma unroll
      for (int r = 0; r < 16; ++r) { p[r] = s0[r]; p[16 + r] = s1[r]; }
      if (!full) {
#pragma unroll
        for (int r = 0; r < 32; ++r) {
          const int kk = kv0 + (r >> 4) * 32 + 4 * hi + (r & 3) + 8 * ((r >> 2) & 3);
          p[r] = ((u32)(iq - kk) < (u32)WINDOW) ? p[r] : -3.0e38f;
        }
      }
      float tm = p[0];
#pragma unroll
      for (int r = 1; r < 32; ++r) tm = fmaxf(tm, p[r]);
      tm = fmaxf(tm, __shfl_xor(tm, 32, 64));
      const float mn = fmaxf(m, tm);
      const float al = __expf(m - mn);
      m = mn;
      float rs = 0.f;
#pragma unroll
      for (int r = 0; r < 32; ++r) { p[r] = __expf(p[r] - mn); rs += p[r]; }
      rs += __shfl_xor(rs, 32, 64);
      lsum = lsum * al + rs;
#pragma unroll
      for (int n = 0; n < 4; ++n)
#pragma unroll
        for (int r = 0; r < 16; ++r) o[n][r] *= al;

      short8 pf[4];
#pragma unroll
      for (int ks = 0; ks < 4; ++ks) {
        const int bb = (ks >> 1) * 16 + (ks & 1) * 8;
        u32 a0 = pk_bf16(p[bb + 0], p[bb + 1]);
        u32 b0 = pk_bf16(p[bb + 4], p[bb + 5]);
        u32 a1 = pk_bf16(p[bb + 2], p[bb + 3]);
        u32 b1 = pk_bf16(p[bb + 6], p[bb + 7]);
        asm volatile("v_permlane32_swap_b32 %0, %1" : "+v"(a0), "+v"(b0));
        asm volatile("v_permlane32_swap_b32 %0, %1" : "+v"(a1), "+v"(b1));
        union { u32 u[4]; short8 s; } uu;
        uu.u[0] = a0; uu.u[1] = a1; uu.u[2] = b0; uu.u[3] = b1;
        pf[ks] = uu.s;
      }
#pragma unroll
      for (int dt = 0; dt < 4; ++dt) {
        const int d = l31 + 32 * dt;
        const int dsw = d & 7;
#pragma unroll
        for (int ks = 0; ks < 4; ++ks) {
          const int rg = ks * 2 + hi;
          const short8 vf = *(const short8*)&sVT[(d * 8 + (rg ^ dsw)) * 8];
          o[dt] = __builtin_amdgcn_mfma_f32_32x32x16_bf16(vf, pf[ks], o[dt], 0, 0, 0);
        }
      }
    }
    __syncthreads();
  }

  __syncthreads();
  float* R = ((float*)sK) + w * 1024;
  const float rl = 1.0f / lsum;
  const int half = hi;
#pragma unroll
  for (int dt = 0; dt < 4; ++dt) {
#pragma unroll
    for (int r = 0; r < 16; ++r) {
      const int dp = 4 * hi + (r & 3) + 8 * (r >> 2);
      R[dp * 32 + (l31 ^ (4 * (dp & 7)))] = o[dt][r] * rl;
    }
    __syncthreads();
    union { u16 hh[16]; short8 s[2]; } U;
#pragma unroll
    for (int j = 0; j < 16; ++j) {
      const int dp = half * 16 + j;
      U.hh[j] = f2b(R[dp * 32 + (l31 ^ (4 * (dp & 7)))]);
    }
    u16* dst = AO + (tokbase + q0 + w * 32 + l31) * (NH * HD) + h * HD + dt * 32 + half * 16;
    *(short8*)dst = U.s[0];
    *(short8*)(dst + 8) = U.s[1];
    __syncthreads();
  }
}

// ---------------- launch ----------------
extern "C" void kernel_launch(void* const* d_in, const int* in_sizes, int n_in,
                              void* d_out, int out_size, void* d_ws, size_t ws_size,
                              hipStream_t stream) {
  const float* hs   = (const float*)d_in[0];
  const float* cosb = (const float*)d_in[1];
  const float* sinb = (const float*)d_in[2];
  const float* Wq   = (const float*)d_in[3];
  const float* Wk   = (const float*)d_in[4];
  const float* Wv   = (const float*)d_in[5];
  const float* Wo   = (const float*)d_in[6];
  const float* qw   = (const float*)d_in[7];
  const float* kw   = (const float*)d_in[8];
  float* out = (float*)d_out;

  const long SZ_X  = (long)BATCH * S_LEN * HID;
  const long SZ_WQ = (long)NH * HD * HID;
  const long SZ_WK = (long)NKV * HD * HID;
  u16* Xb   = (u16*)d_ws;
  u16* Wqb  = Xb + SZ_X;
  u16* Wkb  = Wqb + SZ_WQ;
  u16* Wvb  = Wkb + SZ_WK;
  u16* Wob  = Wvb + SZ_WK;
  u16* QKVb = Wob + SZ_WQ;
  u16* AOb  = QKVb + (long)BATCH * S_LEN * QKVW;

  k_conv<<<2048, 256, 0, stream>>>(hs, Xb, (int)(SZ_X / 4));
  k_conv<<<1024, 256, 0, stream>>>(Wq, Wqb, (int)(SZ_WQ / 4));
  k_conv<<<512, 256, 0, stream>>>(Wk, Wkb, (int)(SZ_WK / 4));
  k_conv<<<512, 256, 0, stream>>>(Wv, Wvb, (int)(SZ_WK / 4));
  k_conv<<<1024, 256, 0, stream>>>(Wo, Wob, (int)(SZ_WQ / 4));

  // fused QKV projection: 4096 x 4096 x 2048, 256 blocks
  k_gemm4p<u16><<<dim3(16, 16), 512, 0, stream>>>(
      Xb, Wqb, QKVb, BATCH * S_LEN, QKVW, HID);

  k_normrope<<<(BATCH * S_LEN * (NH + NKV)) / 4, 256, 0, stream>>>(QKVb, cosb, sinb, qw, kw);

  k_attn<<<dim3(S_LEN / 128, NH, BATCH), 256, 0, stream>>>(QKVb, AOb);

  // output projection: 4096 x 2048 x 2048, 128 blocks
  k_gemm4p<float><<<dim3(8, 16), 512, 0, stream>>>(
      AOb, Wob, out, BATCH * S_LEN, HID, HID);
}

// Round 5
// 213.352 us; speedup vs baseline: 1.8233x; 1.0892x over previous
//
#include <hip/hip_runtime.h>
#include <stdint.h>

#define S_LEN 2048
#define BATCH 2
#define HID 2048
#define NH 16
#define NKV 8
#define HD 128
#define WINDOW 1024
#define SCALE 0.08838834764831845f
#define QKVW 4096

typedef unsigned short u16;
typedef unsigned int u32;
typedef __attribute__((ext_vector_type(8))) short short8;
typedef __attribute__((ext_vector_type(4))) float f32x4;
typedef __attribute__((ext_vector_type(16))) float f32x16;
typedef __attribute__((ext_vector_type(4))) u16 u16x4;

__device__ __forceinline__ u16 f2b(float f) {
  u32 u = __builtin_bit_cast(u32, f);
  return (u16)((u + 0x7fffu + ((u >> 16) & 1u)) >> 16);
}
__device__ __forceinline__ float b2f(u16 h) {
  u32 u = ((u32)h) << 16;
  return __builtin_bit_cast(float, u);
}
__device__ __forceinline__ u32 pk_bf16(float a, float b) {
  u32 d;
  asm("v_cvt_pk_bf16_f32 %0, %1, %2" : "=v"(d) : "v"(a), "v"(b));
  return d;
}

__device__ __forceinline__ void gload_lds16(const u16* g, u16* l) {
  __builtin_amdgcn_global_load_lds(
      (const __attribute__((address_space(1))) u32*)g,
      (__attribute__((address_space(3))) u32*)l, 16, 0, 0);
}

template <int N>
__device__ __forceinline__ void wait_vm() {
  if constexpr (N == 0) asm volatile("s_waitcnt vmcnt(0)" ::: "memory");
  else if constexpr (N == 3) asm volatile("s_waitcnt vmcnt(3)" ::: "memory");
  else if constexpr (N == 4) asm volatile("s_waitcnt vmcnt(4)" ::: "memory");
}

// ---------------- f32 -> bf16 convert ----------------
__global__ __launch_bounds__(256) void k_conv(const float* __restrict__ src,
                                              u16* __restrict__ dst, int n4) {
  int i = blockIdx.x * blockDim.x + threadIdx.x;
  int st = gridDim.x * blockDim.x;
  for (; i < n4; i += st) {
    f32x4 v = ((const f32x4*)src)[i];
    u16x4 o;
    o[0] = f2b(v[0]); o[1] = f2b(v[1]); o[2] = f2b(v[2]); o[3] = f2b(v[3]);
    ((u16x4*)dst)[i] = o;
  }
}

__device__ __forceinline__ void store_c(u16* C, long idx, float v) { C[idx] = f2b(v); }
__device__ __forceinline__ void store_c(float* C, long idx, float v) { C[idx] = v; }

// ---- GEMM C = A*B^T, 256xBN tile, BK=64, 8-phase / 2-K-tile pipeline (m201 port)
// K-tile u -> buffer u&1 (iterations process (even,odd) pairs -> fixed bufs).
// One half-tile staged per phase, ledger order {A1(u+1),B0(u+1),A0(u+2),
// B1(u+2),A1(u+2),B0(u+2),A0(u+3),B1(u+3)}; vmcnt(AL+BL) once per K-tile
// (phases 4 and 8): guarantees the NEXT K-tile's 4 halves landed, leaving the
// newest 2 stages in flight. Every restage is >=1 barrier after the slot's
// last ds_read. sched_barrier(0) after each closing barrier pins ds_reads
// below the wait that legalizes them.
#define LOADAF(BUF, MQ)                                                         \
  _Pragma("unroll") for (int i_ = 0; i_ < 4; ++i_) {                            \
    af[i_][0] = *(const short8*)&sA[BUF][arow + ((MQ)*64 + i_*16) * 64 + akc0]; \
    af[i_][1] = *(const short8*)&sA[BUF][arow + ((MQ)*64 + i_*16) * 64 + akc1]; \
  }
#define LOADBF(BUF, NQ)                                                         \
  _Pragma("unroll") for (int j_ = 0; j_ < NIH; ++j_) {                          \
    bf[j_][0] = *(const short8*)&sB[BUF][brow + ((NQ)*QB + j_*16) * 64 + akc0]; \
    bf[j_][1] = *(const short8*)&sB[BUF][brow + ((NQ)*QB + j_*16) * 64 + akc1]; \
  }
#define STAGE_A(H, BUF, KT)                                            \
  _Pragma("unroll") for (int i_ = 0; i_ < 2; ++i_)                     \
      gload_lds16(Abase + aOff[H][i_] + (KT) * 64, &sA[BUF][aDst[H][i_]]);
#define STAGE_B(H, BUF, KT)                                            \
  _Pragma("unroll") for (int i_ = 0; i_ < BL; ++i_)                    \
      gload_lds16(Bbase + bOff[H][i_] + (KT) * 64, &sB[BUF][bDst[H][i_]]);
#define MFMAQ(MQ, NQ)                                                           \
  __builtin_amdgcn_s_setprio(1);                                                \
  _Pragma("unroll") for (int i_ = 0; i_ < 4; ++i_) {                            \
    _Pragma("unroll") for (int j_ = 0; j_ < NIH; ++j_) {                        \
      acc[(MQ)*4 + i_][(NQ)*NIH + j_] = __builtin_amdgcn_mfma_f32_16x16x32_bf16(\
          af[i_][0], bf[j_][0], acc[(MQ)*4 + i_][(NQ)*NIH + j_], 0, 0, 0);      \
      acc[(MQ)*4 + i_][(NQ)*NIH + j_] = __builtin_amdgcn_mfma_f32_16x16x32_bf16(\
          af[i_][1], bf[j_][1], acc[(MQ)*4 + i_][(NQ)*NIH + j_], 0, 0, 0);      \
    }                                                                           \
  }                                                                             \
  __builtin_amdgcn_s_setprio(0);
#define OPEN_MFMA()                                      \
  __builtin_amdgcn_sched_barrier(0);                     \
  __builtin_amdgcn_s_barrier();                          \
  asm volatile("s_waitcnt lgkmcnt(0)" ::: "memory");     \
  __builtin_amdgcn_sched_barrier(0);
#define CLOSEP()                                         \
  __builtin_amdgcn_s_barrier();                          \
  __builtin_amdgcn_sched_barrier(0);

template <int BN, typename OutT>
__global__ __launch_bounds__(512, 1) void k_gemm8p(const u16* __restrict__ A,
                                                   const u16* __restrict__ B,
                                                   OutT* __restrict__ C,
                                                   int M, int N, int K) {
  constexpr int NIH = BN / 128;   // bf frags per n-quadrant
  constexpr int NI = 2 * NIH;
  constexpr int BL = BN / 128;    // B gloads per thread per half
  constexpr int QB = BN / 8;      // B interleave block (rows)
  constexpr int WV = 2 + BL;      // steady vmcnt (2 stages in flight)

  __shared__ u16 sA[2][256 * 64];
  __shared__ u16 sB[2][BN * 64];
  const int tid = threadIdx.x;
  const int lane = tid & 63;
  const int w = tid >> 6;
  const int l15 = lane & 15;
  const int lg = lane >> 4;
  const int wm = w >> 2;
  const int wn = w & 3;
  const int sw = l15 & 7;

  const int gx = gridDim.x;
  const int nwg = gx * gridDim.y;
  const int flat = blockIdx.y * gx + blockIdx.x;
  const int tile = (flat & 7) * (nwg >> 3) + (flat >> 3);
  const long m0 = (long)(tile / gx) * 256;
  const long n0 = (long)(tile % gx) * BN;

  const u16* Abase = A + m0 * K;
  const u16* Bbase = B + n0 * K;

  int aOff[2][2], aDst[2][2], bOff[2][2], bDst[2][2];
#pragma unroll
  for (int h = 0; h < 2; ++h) {
#pragma unroll
    for (int i = 0; i < 2; ++i) {
      const int c = tid + i * 512;
      const int lr = c >> 3, chs = c & 7;
      const int grA = ((lr >> 6) << 7) + (h << 6) + (lr & 63);
      aOff[h][i] = grA * K + (chs ^ (grA & 7)) * 8;
      aDst[h][i] = grA * 64 + chs * 8;
    }
#pragma unroll
    for (int i = 0; i < BL; ++i) {
      const int c = tid + i * 512;
      const int lr = c >> 3, chs = c & 7;
      const int grB = (lr / QB) * (2 * QB) + h * QB + (lr % QB);
      bOff[h][i] = grB * K + (chs ^ (grB & 7)) * 8;
      bDst[h][i] = grB * 64 + chs * 8;
    }
  }

  f32x4 acc[8][NI];
  const f32x4 z4 = {0.f, 0.f, 0.f, 0.f};
#pragma unroll
  for (int i = 0; i < 8; ++i)
#pragma unroll
    for (int j = 0; j < NI; ++j) acc[i][j] = z4;

  const int arow = (wm * 128 + l15) * 64;
  const int brow = (wn * (BN / 4) + l15) * 64;
  const int akc0 = (lg ^ sw) * 8;
  const int akc1 = ((4 + lg) ^ sw) * 8;

  const int NT = K >> 6;
  const int NIT = NT >> 1;
  short8 af[4][2], bf[NIH][2];

  // prologue: K-tile 0 fully + A0(1), B1(1); leave newest 2 stages in flight
  STAGE_A(0, 0, 0) STAGE_B(0, 0, 0) STAGE_B(1, 0, 0) STAGE_A(1, 0, 0)
  STAGE_A(0, 1, 1) STAGE_B(1, 1, 1)
  wait_vm<WV>();
  CLOSEP()

  for (int it = 0; it < NIT - 1; ++it) {
    const int u = 2 * it;
    // ph1: u (buf0), Q(m-lo,n-lo)
    LOADAF(0, 0) LOADBF(0, 0)
    STAGE_A(1, 1, u + 1)
    OPEN_MFMA()
    MFMAQ(0, 0)
    CLOSEP()
    // ph2: Q(m-lo,n-hi)
    LOADBF(0, 1)
    STAGE_B(0, 1, u + 1)
    OPEN_MFMA()
    MFMAQ(0, 1)
    CLOSEP()
    // ph3: Q(m-hi,n-hi)
    LOADAF(0, 1)
    STAGE_A(0, 0, u + 2)
    OPEN_MFMA()
    MFMAQ(1, 1)
    CLOSEP()
    // ph4: Q(m-hi,n-lo); wait legalizes K-tile u+1
    LOADBF(0, 0)
    STAGE_B(1, 0, u + 2)
    wait_vm<WV>();
    OPEN_MFMA()
    MFMAQ(1, 0)
    CLOSEP()
    // ph5: u+1 (buf1), Q(m-lo,n-lo)
    LOADAF(1, 0) LOADBF(1, 0)
    STAGE_A(1, 0, u + 2)
    OPEN_MFMA()
    MFMAQ(0, 0)
    CLOSEP()
    // ph6
    LOADBF(1, 1)
    STAGE_B(0, 0, u + 2)
    OPEN_MFMA()
    MFMAQ(0, 1)
    CLOSEP()
    // ph7
    LOADAF(1, 1)
    STAGE_A(0, 1, u + 3)
    OPEN_MFMA()
    MFMAQ(1, 1)
    CLOSEP()
    // ph8; wait legalizes K-tile u+2
    LOADBF(1, 0)
    STAGE_B(1, 1, u + 3)
    wait_vm<WV>();
    OPEN_MFMA()
    MFMAQ(1, 0)
    CLOSEP()
  }
  // peeled last iteration (u = NT-2, NT-1): finish staging u+1, no u+2/u+3
  {
    const int u = NT - 2;
    LOADAF(0, 0) LOADBF(0, 0)
    STAGE_A(1, 1, u + 1)
    OPEN_MFMA()
    MFMAQ(0, 0)
    CLOSEP()
    LOADBF(0, 1)
    STAGE_B(0, 1, u + 1)
    OPEN_MFMA()
    MFMAQ(0, 1)
    CLOSEP()
    LOADAF(0, 1)
    OPEN_MFMA()
    MFMAQ(1, 1)
    CLOSEP()
    LOADBF(0, 0)
    wait_vm<0>();
    OPEN_MFMA()
    MFMAQ(1, 0)
    CLOSEP()
    LOADAF(1, 0) LOADBF(1, 0)
    OPEN_MFMA()
    MFMAQ(0, 0)
    CLOSEP()
    LOADBF(1, 1)
    OPEN_MFMA()
    MFMAQ(0, 1)
    CLOSEP()
    LOADAF(1, 1)
    OPEN_MFMA()
    MFMAQ(1, 1)
    CLOSEP()
    LOADBF(1, 0)
    OPEN_MFMA()
    MFMAQ(1, 0)
    CLOSEP()
  }

#pragma unroll
  for (int mi = 0; mi < 8; ++mi)
#pragma unroll
    for (int ni = 0; ni < NI; ++ni)
#pragma unroll
      for (int r = 0; r < 4; ++r) {
        long row = m0 + wm * 128 + mi * 16 + lg * 4 + r;
        long col = n0 + wn * (BN / 4) + ni * 16 + l15;
        store_c(C, row * (long)N + col, acc[mi][ni][r]);
      }
}

// ---------------- RMSNorm + RoPE (in place on fused QKV, bf16) ----------------
__global__ __launch_bounds__(256) void k_normrope(u16* __restrict__ QKV,
                                                  const float* __restrict__ cosb,
                                                  const float* __restrict__ sinb,
                                                  const float* __restrict__ qw,
                                                  const float* __restrict__ kw) {
  const int lane = threadIdx.x & 63;
  const int w = threadIdx.x >> 6;
  int row = blockIdx.x * 4 + w;
  const int nQ = BATCH * S_LEN * NH;
  u16* p;
  const float* nw;
  int tok;
  float sc;
  if (row < nQ) {
    tok = row >> 4;
    int h = row & 15;
    p = QKV + (long)tok * QKVW + h * HD;
    nw = qw;
    sc = SCALE;
  } else {
    int r2 = row - nQ;
    tok = r2 >> 3;
    int h = r2 & 7;
    p = QKV + (long)tok * QKVW + 2048 + h * HD;
    nw = kw;
    sc = 1.0f;
  }
  float x0 = b2f(p[lane]);
  float x1 = b2f(p[lane + 64]);
  float ss = x0 * x0 + x1 * x1;
#pragma unroll
  for (int mk = 1; mk < 64; mk <<= 1) ss += __shfl_xor(ss, mk, 64);
  float rinv = rsqrtf(ss * (1.0f / 128.0f) + 1e-6f);
  float y0 = x0 * rinv * nw[lane];
  float y1 = x1 * rinv * nw[lane + 64];
  const float* cp = cosb + (long)tok * HD;
  const float* sp = sinb + (long)tok * HD;
  float o0 = (y0 * cp[lane] - y1 * sp[lane]) * sc;
  float o1 = (y1 * cp[lane + 64] + y0 * sp[lane + 64]) * sc;
  p[lane] = f2b(o0);
  p[lane + 64] = f2b(o1);
}

// ---------------- Flash attention (unchanged) ----------------
__global__ __launch_bounds__(256, 2) void k_attn(const u16* __restrict__ QKV,
                                                 u16* __restrict__ AO) {
  __shared__ u16 sK[64 * 128];
  __shared__ u16 sVT[64 * 128];
  const int tid = threadIdx.x;
  const int lane = tid & 63;
  const int l31 = lane & 31;
  const int hi = lane >> 5;
  const int w = tid >> 6;
  const int q0 = blockIdx.x * 128;
  const int h = blockIdx.y;
  const int b = blockIdx.z;
  const int kvh = h >> 1;
  const int qw0 = q0 + w * 32;
  const int iq = qw0 + l31;

  const long tokbase = (long)b * S_LEN;
  const u16* Qrow = QKV + (tokbase + qw0 + l31) * QKVW + h * HD;
  short8 qf[8];
#pragma unroll
  for (int dt = 0; dt < 8; ++dt) qf[dt] = *(const short8*)(Qrow + dt * 16 + hi * 8);

  f32x16 o[4];
#pragma unroll
  for (int n = 0; n < 4; ++n)
#pragma unroll
    for (int r = 0; r < 16; ++r) o[n][r] = 0.f;
  float m = 0.f, lsum = 0.f;

  const u16* Kbase = QKV + tokbase * QKVW + 2048 + kvh * HD;
  const u16* Vbase = QKV + tokbase * QKVW + 3072 + kvh * HD;

  int kc_row[4], kc_off[4];
  u16* kc_dst[4];
#pragma unroll
  for (int i = 0; i < 4; ++i) {
    const int c = tid + 256 * i;
    kc_row[i] = c >> 4;
    kc_off[i] = (((c & 15) ^ ((c >> 4) & 7))) * 8;
    kc_dst[i] = &sK[c * 8];
  }
  const int rp = tid & 31;
  const int dc0 = tid >> 5;
  const int rg_st = rp >> 2;

  int t_lo = q0 - (WINDOW - 1);
  t_lo = (t_lo < 0 ? 0 : t_lo) >> 6;
  const int t_hi = (q0 + 127) >> 6;

  for (int t = t_lo; t <= t_hi; ++t) {
    const int kv0 = t << 6;
#pragma unroll
    for (int i = 0; i < 4; ++i)
      gload_lds16(Kbase + (long)(kv0 + kc_row[i]) * QKVW + kc_off[i], kc_dst[i]);
#pragma unroll
    for (int i = 0; i < 2; ++i) {
      const int dc = dc0 + i * 8;
      const u16* vp = Vbase + (long)(kv0 + 2 * rp) * QKVW + dc * 8;
      short8 v0 = *(const short8*)vp;
      short8 v1 = *(const short8*)(vp + QKVW);
#pragma unroll
      for (int e = 0; e < 8; ++e) {
        const int d = dc * 8 + e;
        const int unit = d * 8 + (rg_st ^ (d & 7));
        ((u32*)sVT)[unit * 4 + (rp & 3)] = (u32)(u16)v0[e] | ((u32)(u16)v1[e] << 16);
      }
    }
    __syncthreads();

    const bool skipw = (kv0 > qw0 + 31) || (kv0 + 63 < qw0 - (WINDOW - 1));
    if (!skipw) {
      const bool full = (kv0 + 63 <= qw0) && ((qw0 + 31) - kv0 < WINDOW);
      f32x16 s0, s1;
#pragma unroll
      for (int r = 0; r < 16; ++r) { s0[r] = 0.f; s1[r] = 0.f; }
      const int rsw = l31 & 7;
#pragma unroll
      for (int dt = 0; dt < 8; ++dt) {
        const int ch = hi + 2 * dt;
        const short8 kf0 = *(const short8*)&sK[(l31 * 16 + (ch ^ rsw)) * 8];
        s0 = __builtin_amdgcn_mfma_f32_32x32x16_bf16(kf0, qf[dt], s0, 0, 0, 0);
        const short8 kf1 = *(const short8*)&sK[((l31 + 32) * 16 + (ch ^ rsw)) * 8];
        s1 = __builtin_amdgcn_mfma_f32_32x32x16_bf16(kf1, qf[dt], s1, 0, 0, 0);
      }
      float p[32];
#pragma unroll
      for (int r = 0; r < 16; ++r) { p[r] = s0[r]; p[16 + r] = s1[r]; }
      if (!full) {
#pragma unroll
        for (int r = 0; r < 32; ++r) {
          const int kk = kv0 + (r >> 4) * 32 + 4 * hi + (r & 3) + 8 * ((r >> 2) & 3);
          p[r] = ((u32)(iq - kk) < (u32)WINDOW) ? p[r] : -3.0e38f;
        }
      }
      float tm = p[0];
#pragma unroll
      for (int r = 1; r < 32; ++r) tm = fmaxf(tm, p[r]);
      tm = fmaxf(tm, __shfl_xor(tm, 32, 64));
      const float mn = fmaxf(m, tm);
      const float al = __expf(m - mn);
      m = mn;
      float rs = 0.f;
#pragma unroll
      for (int r = 0; r < 32; ++r) { p[r] = __expf(p[r] - mn); rs += p[r]; }
      rs += __shfl_xor(rs, 32, 64);
      lsum = lsum * al + rs;
#pragma unroll
      for (int n = 0; n < 4; ++n)
#pragma unroll
        for (int r = 0; r < 16; ++r) o[n][r] *= al;

      short8 pf[4];
#pragma unroll
      for (int ks = 0; ks < 4; ++ks) {
        const int bb = (ks >> 1) * 16 + (ks & 1) * 8;
        u32 a0 = pk_bf16(p[bb + 0], p[bb + 1]);
        u32 b0 = pk_bf16(p[bb + 4], p[bb + 5]);
        u32 a1 = pk_bf16(p[bb + 2], p[bb + 3]);
        u32 b1 = pk_bf16(p[bb + 6], p[bb + 7]);
        asm volatile("v_permlane32_swap_b32 %0, %1" : "+v"(a0), "+v"(b0));
        asm volatile("v_permlane32_swap_b32 %0, %1" : "+v"(a1), "+v"(b1));
        union { u32 u[4]; short8 s; } uu;
        uu.u[0] = a0; uu.u[1] = a1; uu.u[2] = b0; uu.u[3] = b1;
        pf[ks] = uu.s;
      }
#pragma unroll
      for (int dt = 0; dt < 4; ++dt) {
        const int d = l31 + 32 * dt;
        const int dsw = d & 7;
#pragma unroll
        for (int ks = 0; ks < 4; ++ks) {
          const int rg = ks * 2 + hi;
          const short8 vf = *(const short8*)&sVT[(d * 8 + (rg ^ dsw)) * 8];
          o[dt] = __builtin_amdgcn_mfma_f32_32x32x16_bf16(vf, pf[ks], o[dt], 0, 0, 0);
        }
      }
    }
    __syncthreads();
  }

  __syncthreads();
  float* R = ((float*)sK) + w * 1024;
  const float rl = 1.0f / lsum;
  const int half = hi;
#pragma unroll
  for (int dt = 0; dt < 4; ++dt) {
#pragma unroll
    for (int r = 0; r < 16; ++r) {
      const int dp = 4 * hi + (r & 3) + 8 * (r >> 2);
      R[dp * 32 + (l31 ^ (4 * (dp & 7)))] = o[dt][r] * rl;
    }
    __syncthreads();
    union { u16 hh[16]; short8 s[2]; } U;
#pragma unroll
    for (int j = 0; j < 16; ++j) {
      const int dp = half * 16 + j;
      U.hh[j] = f2b(R[dp * 32 + (l31 ^ (4 * (dp & 7)))]);
    }
    u16* dst = AO + (tokbase + q0 + w * 32 + l31) * (NH * HD) + h * HD + dt * 32 + half * 16;
    *(short8*)dst = U.s[0];
    *(short8*)(dst + 8) = U.s[1];
    __syncthreads();
  }
}

// ---------------- launch ----------------
extern "C" void kernel_launch(void* const* d_in, const int* in_sizes, int n_in,
                              void* d_out, int out_size, void* d_ws, size_t ws_size,
                              hipStream_t stream) {
  const float* hs   = (const float*)d_in[0];
  const float* cosb = (const float*)d_in[1];
  const float* sinb = (const float*)d_in[2];
  const float* Wq   = (const float*)d_in[3];
  const float* Wk   = (const float*)d_in[4];
  const float* Wv   = (const float*)d_in[5];
  const float* Wo   = (const float*)d_in[6];
  const float* qw   = (const float*)d_in[7];
  const float* kw   = (const float*)d_in[8];
  float* out = (float*)d_out;

  const long SZ_X  = (long)BATCH * S_LEN * HID;
  const long SZ_WQ = (long)NH * HD * HID;
  const long SZ_WK = (long)NKV * HD * HID;
  u16* Xb   = (u16*)d_ws;
  u16* Wqb  = Xb + SZ_X;
  u16* Wkb  = Wqb + SZ_WQ;
  u16* Wvb  = Wkb + SZ_WK;
  u16* Wob  = Wvb + SZ_WK;
  u16* QKVb = Wob + SZ_WQ;
  u16* AOb  = QKVb + (long)BATCH * S_LEN * QKVW;

  k_conv<<<2048, 256, 0, stream>>>(hs, Xb, (int)(SZ_X / 4));
  k_conv<<<1024, 256, 0, stream>>>(Wq, Wqb, (int)(SZ_WQ / 4));
  k_conv<<<512, 256, 0, stream>>>(Wk, Wkb, (int)(SZ_WK / 4));
  k_conv<<<512, 256, 0, stream>>>(Wv, Wvb, (int)(SZ_WK / 4));
  k_conv<<<1024, 256, 0, stream>>>(Wo, Wob, (int)(SZ_WQ / 4));

  // fused QKV projection: 4096 x 4096 x 2048, 256 blocks (16x16)
  k_gemm8p<256, u16><<<dim3(16, 16), 512, 0, stream>>>(
      Xb, Wqb, QKVb, BATCH * S_LEN, QKVW, HID);

  k_normrope<<<(BATCH * S_LEN * (NH + NKV)) / 4, 256, 0, stream>>>(QKVb, cosb, sinb, qw, kw);

  k_attn<<<dim3(S_LEN / 128, NH, BATCH), 256, 0, stream>>>(QKVb, AOb);

  // output projection: 4096 x 2048 x 2048, BN=128 -> 256 blocks (16x16)
  k_gemm8p<128, float><<<dim3(16, 16), 512, 0, stream>>>(
      AOb, Wob, out, BATCH * S_LEN, HID, HID);
}